// Round 7
// baseline (2940.456 us; speedup 1.0000x reference)
//
#include <hip/hip_runtime.h>
#include <math.h>

#define H 128
#define H4 (H/4)
#define KK 12
#define MSUB 4
#define FF 120000
#define SS 10000
#define NN 2500
#define NBATCH 50
#define NLAYER 4
#define EINTRA 240000
#define EINTER 40000
#define HH (H*H)
#define BN_EPS 1e-5f
#define CAP_I 32
#define CAP_E 96
#define WF_SHORTS 16384   // per matrix per split: 128*128
#define ZPAD 132

typedef short short8 __attribute__((ext_vector_type(8)));
typedef float floatx4 __attribute__((ext_vector_type(4)));

__device__ __forceinline__ unsigned short f2bf_rne(float x){
  unsigned u = __float_as_uint(x);
  unsigned r = u + 0x7FFFu + ((u >> 16) & 1u);
  return (unsigned short)(r >> 16);
}

// ---------------- small helpers ----------------

__global__ void k_zeroi(int* __restrict__ p, int n){
  int i = blockIdx.x*256 + threadIdx.x;
  if (i < n) p[i] = 0;
}

// ---------------- CSR bucket build ----------------

__global__ void k_bucket(const int* __restrict__ dst, int E, int* __restrict__ cnt,
                         int* __restrict__ beid, int cap){
  int e = blockIdx.x*256 + threadIdx.x;
  if (e >= E) return;
  int d = dst[e];
  int p = atomicAdd(&cnt[d], 1);
  if (p < cap) beid[(size_t)d*cap + p] = e;
}

__global__ void k_scan(const int* __restrict__ cnt, int rows, int cap,
                       int* __restrict__ rowptr, int* __restrict__ gcount){
  __shared__ int sdata[256];
  __shared__ int sbase;
  int tid = threadIdx.x;
  int r = blockIdx.x*256 + tid;
  int v = 0;
  if (r < rows){ v = cnt[r]; if (v > cap) v = cap; }
  sdata[tid] = v;
  __syncthreads();
  for (int ofs = 1; ofs < 256; ofs <<= 1){
    int t = (tid >= ofs) ? sdata[tid-ofs] : 0;
    __syncthreads();
    sdata[tid] += t;
    __syncthreads();
  }
  if (tid == 255) sbase = atomicAdd(gcount, sdata[255]);
  __syncthreads();
  if (r < rows) rowptr[r] = sbase + sdata[tid] - v;
}

__global__ void k_csr_fill(const int* __restrict__ cnt, const int* __restrict__ rowptr,
                           const int* __restrict__ beid, const int* __restrict__ src,
                           int rows, int cap, int2* __restrict__ es){
  int f = blockIdx.x*256 + threadIdx.x;
  if (f >= rows) return;
  int n = cnt[f]; if (n > cap) n = cap;
  int base = rowptr[f];
  const int* bl = beid + (size_t)f*cap;
  for (int i = 0; i < n; ++i){
    int e = bl[i];
    es[base + i] = make_int2(e, src[e]);
  }
}

// ---------------- W split prep (frag-major hi+lo), once ----------------
// idx per matrix: (ks*8+nt)*512 + lane*8 + j; 24 mats: layer*6 + {0=iW1,1=iW2,2=selfW,3=rootW,4=inW1,5=inW2}

__global__ void k_wprep(const float* __restrict__ iW1, const float* __restrict__ iW2,
                        const float* __restrict__ sW,  const float* __restrict__ rW,
                        const float* __restrict__ nW1, const float* __restrict__ nW2,
                        short* __restrict__ whiG, short* __restrict__ wloG){
  int mat = blockIdx.x >> 3;                      // 24 matrices, 8 blocks each
  int t = (blockIdx.x & 7)*256 + threadIdx.x;     // 0..2047 : (ks,nt,lane)
  int l = t & 63, nt = (t >> 6) & 7, ks = t >> 9;
  int layer = mat / 6, which = mat % 6;
  const float* W;
  switch (which){
    case 0: W = iW1; break; case 1: W = iW2; break; case 2: W = sW; break;
    case 3: W = rW;  break; case 4: W = nW1; break; default: W = nW2; break;
  }
  W += (size_t)layer*HH;
  short* oh = whiG + (size_t)mat*WF_SHORTS;
  short* ol = wloG + (size_t)mat*WF_SHORTS;
  int quad = l >> 4, n15 = l & 15;
  #pragma unroll
  for (int j = 0; j < 8; ++j){
    int k = ks*32 + quad*8 + j;
    int n = nt*16 + n15;
    float v = W[(size_t)k*H + n];
    unsigned short hb = f2bf_rne(v);
    float hf = __uint_as_float((unsigned)hb << 16);
    int idx = (ks*8 + nt)*512 + l*8 + j;
    oh[idx] = (short)hb;
    ol[idx] = (short)f2bf_rne(v - hf);
  }
}

// ---------------- input encoding ----------------

__global__ void k_encode(float* __restrict__ h, const int* __restrict__ xtok,
                         const int* __restrict__ dist, const int* __restrict__ nids,
                         const int* __restrict__ subb, const float* __restrict__ lp,
                         const float* __restrict__ aemb, const float* __restrict__ demb,
                         const float* __restrict__ lw, const float* __restrict__ lb){
  int idx = blockIdx.x*256 + threadIdx.x;
  if (idx >= FF*H4) return;
  int f = idx >> 5; int c = (idx & 31) << 2;
  float vf = (nids[f] >= 0) ? 1.f : 0.f;
  float l = lp[subb[f]];
  float4 a = *(const float4*)(aemb + (size_t)xtok[f]*H + c);
  float4 d = *(const float4*)(demb + (size_t)dist[f]*H + c);
  float4 w = *(const float4*)(lw + c);
  float4 b = *(const float4*)(lb + c);
  float4 o;
  o.x = (a.x + d.x + fmaxf(fmaf(l, w.x, b.x), 0.f)) * vf;
  o.y = (a.y + d.y + fmaxf(fmaf(l, w.y, b.y), 0.f)) * vf;
  o.z = (a.z + d.z + fmaxf(fmaf(l, w.z, b.z), 0.f)) * vf;
  o.w = (a.w + d.w + fmaxf(fmaf(l, w.w, b.w), 0.f)) * vf;
  *(float4*)(h + (size_t)f*H + c) = o;
}

// ---------------- HT weights ----------------

__global__ void k_htw(const int* __restrict__ nids, const int* __restrict__ rfi,
                      const float* __restrict__ lp, const float* __restrict__ alpha,
                      float* __restrict__ htw){
  int n = blockIdx.x*256 + threadIdx.x;
  if (n >= NN) return;
  float a = alpha[0];
  float w[MSUB]; float sum = 0.f;
  #pragma unroll
  for (int m = 0; m < MSUB; ++m){
    int s = n*MSUB + m;
    int rid = nids[rfi[s]];
    float wm = (rid >= 0) ? expf(-a*lp[s]) : 0.f;
    w[m] = wm; sum += wm;
  }
  float inv = 1.f / (sum + 1e-16f);
  #pragma unroll
  for (int m = 0; m < MSUB; ++m) htw[n*MSUB + m] = w[m]*inv;
}

// ---------------- GINE gather (CSR form) ----------------

__global__ void k_gine_gather2(float* __restrict__ outa, const float* __restrict__ x,
                               const float* __restrict__ ea, const int* __restrict__ cnt,
                               const int* __restrict__ rowptr, const int2* __restrict__ es,
                               int rows, int cap){
  int idx = blockIdx.x*256 + threadIdx.x;
  if (idx >= rows*H4) return;
  int f = idx >> 5; int c = (idx & 31) << 2;
  float4 acc = *(const float4*)(x + (size_t)f*H + c);
  int n = cnt[f]; if (n > cap) n = cap;
  const int2* p = es + rowptr[f];
  int i = 0;
  for (; i + 2 <= n; i += 2){
    int2 e0 = p[i];
    int2 e1 = p[i+1];
    float4 x0 = *(const float4*)(x + (size_t)e0.y*H + c);
    float4 a0 = *(const float4*)(ea + (size_t)e0.x*H + c);
    float4 x1 = *(const float4*)(x + (size_t)e1.y*H + c);
    float4 a1 = *(const float4*)(ea + (size_t)e1.x*H + c);
    acc.x += fmaxf(x0.x + a0.x, 0.f) + fmaxf(x1.x + a1.x, 0.f);
    acc.y += fmaxf(x0.y + a0.y, 0.f) + fmaxf(x1.y + a1.y, 0.f);
    acc.z += fmaxf(x0.z + a0.z, 0.f) + fmaxf(x1.z + a1.z, 0.f);
    acc.w += fmaxf(x0.w + a0.w, 0.f) + fmaxf(x1.w + a1.w, 0.f);
  }
  if (i < n){
    int2 e0 = p[i];
    float4 x0 = *(const float4*)(x + (size_t)e0.y*H + c);
    float4 a0 = *(const float4*)(ea + (size_t)e0.x*H + c);
    acc.x += fmaxf(x0.x + a0.x, 0.f);
    acc.y += fmaxf(x0.y + a0.y, 0.f);
    acc.z += fmaxf(x0.z + a0.z, 0.f);
    acc.w += fmaxf(x0.w + a0.w, 0.f);
  }
  *(float4*)(outa + (size_t)f*H + c) = acc;
}

// ---------------- HT root gather ----------------

__global__ void k_canon(float* __restrict__ canon, const float* __restrict__ h,
                        const float* __restrict__ htw, const int* __restrict__ rfi){
  int idx = blockIdx.x*256 + threadIdx.x;
  if (idx >= NN*H4) return;
  int n = idx >> 5; int c = (idx & 31) << 2;
  float4 acc = make_float4(0.f,0.f,0.f,0.f);
  #pragma unroll
  for (int m = 0; m < MSUB; ++m){
    int s = n*MSUB + m;
    float w = htw[s];
    const float* p = h + (size_t)rfi[s]*H + c;
    acc.x += w*p[0]; acc.y += w*p[1]; acc.z += w*p[2]; acc.w += w*p[3];
  }
  *(float4*)(canon + (size_t)n*H + c) = acc;
}

// ---------------- MFMA helpers ----------------

__device__ __forceinline__ void conv8(const float* av, short8& ah, short8& al){
  #pragma unroll
  for (int j = 0; j < 8; ++j){
    unsigned short hb = f2bf_rne(av[j]);
    float hf = __uint_as_float((unsigned)hb << 16);
    ah[j] = (short)hb;
    al[j] = (short)f2bf_rne(av[j] - hf);
  }
}

__device__ __forceinline__ void mfma3(floatx4* acc, const short8* ah, const short8* al,
                                      const short* hp, const short* lp){
  #pragma unroll
  for (int ks = 0; ks < 4; ++ks){
    #pragma unroll
    for (int nt = 0; nt < 8; ++nt){
      short8 bh = *(const short8*)(hp + (ks*8 + nt)*512);
      short8 bl = *(const short8*)(lp + (ks*8 + nt)*512);
      acc[nt] = __builtin_amdgcn_mfma_f32_16x16x32_bf16(ah[ks], bh, acc[nt], 0, 0, 0);
      acc[nt] = __builtin_amdgcn_mfma_f32_16x16x32_bf16(al[ks], bh, acc[nt], 0, 0, 0);
      acc[nt] = __builtin_amdgcn_mfma_f32_16x16x32_bf16(ah[ks], bl, acc[nt], 0, 0, 0);
    }
  }
}

// ---------------- generic small matmul (B-frags hi+lo from global, no LDS) ----------------

__global__ __launch_bounds__(256, 2) void k_mm_mfma(
    const float* __restrict__ in, float* __restrict__ out, int rows,
    const short* __restrict__ whi, const short* __restrict__ wlo,
    const float* __restrict__ bias, int do_relu, const int* __restrict__ gather)
{
  int tid = threadIdx.x;
  int w = tid >> 6, l = tid & 63;
  int quad = l >> 4, n15 = l & 15;
  const short* hp = whi + l*8;
  const short* lp = wlo + l*8;

  int ngroups = (rows + 63) >> 6;
  for (int g = blockIdx.x; g < ngroups; g += gridDim.x){
    int rload = g*64 + w*16 + n15;
    bool okload = rload < rows;
    int ir = okload ? (gather ? gather[rload] : rload) : 0;
    const float* ap = in + (size_t)ir*H + quad*8;

    short8 ah[4], al[4];
    #pragma unroll
    for (int ks = 0; ks < 4; ++ks){
      float4 a0 = okload ? *(const float4*)(ap + ks*32 + 0) : make_float4(0.f,0.f,0.f,0.f);
      float4 a1 = okload ? *(const float4*)(ap + ks*32 + 4) : make_float4(0.f,0.f,0.f,0.f);
      float av[8] = {a0.x,a0.y,a0.z,a0.w,a1.x,a1.y,a1.z,a1.w};
      conv8(av, ah[ks], al[ks]);
    }

    floatx4 acc[8] = {};
    mfma3(acc, ah, al, hp, lp);

    int rbase = g*64 + w*16 + quad*4;
    #pragma unroll
    for (int nt = 0; nt < 8; ++nt){
      int col = nt*16 + n15;
      float bv = bias[col];
      #pragma unroll
      for (int reg = 0; reg < 4; ++reg){
        int r = rbase + reg;
        if (r < rows){
          float v = acc[nt][reg] + bv;
          if (do_relu) v = fmaxf(v, 0.f);
          out[(size_t)r*H + col] = v;
        }
      }
    }
  }
}

// ---------------- fused MLP: x = relu(x@W1+b1)@W2 + b2, in-place, + BN-stats partials ----------------
// z and out routed through a per-wave LDS tile [16][ZPAD]; coalesced float4 final stores.
// rows must be a multiple of 64 (FF is).

__global__ __launch_bounds__(256, 2) void k_mlp_fused(
    float* __restrict__ x, int rows,
    const short* __restrict__ whi1, const short* __restrict__ wlo1, const float* __restrict__ b1,
    const short* __restrict__ whi2, const short* __restrict__ wlo2, const float* __restrict__ b2,
    double* __restrict__ part)
{
  __shared__ float zb[4][16][ZPAD];
  int tid = threadIdx.x;
  int w = tid >> 6, l = tid & 63;
  int quad = l >> 4, n15 = l & 15;
  const short* h1 = whi1 + l*8; const short* l1 = wlo1 + l*8;
  const short* h2 = whi2 + l*8; const short* l2 = wlo2 + l*8;
  float (*Z)[ZPAD] = zb[w];

  float s0[8] = {0,0,0,0,0,0,0,0};
  float s1[8] = {0,0,0,0,0,0,0,0};

  int ngroups = rows >> 6;
  for (int g = blockIdx.x; g < ngroups; g += gridDim.x){
    const float* ap = x + (size_t)(g*64 + w*16 + n15)*H + quad*8;
    short8 ah[4], al[4];
    #pragma unroll
    for (int ks = 0; ks < 4; ++ks){
      float4 a0 = *(const float4*)(ap + ks*32 + 0);
      float4 a1 = *(const float4*)(ap + ks*32 + 4);
      float av[8] = {a0.x,a0.y,a0.z,a0.w,a1.x,a1.y,a1.z,a1.w};
      conv8(av, ah[ks], al[ks]);
    }

    floatx4 acc[8] = {};
    mfma3(acc, ah, al, h1, l1);

    // z = relu(acc + b1) -> LDS (C-layout, wave-local)
    #pragma unroll
    for (int nt = 0; nt < 8; ++nt){
      float bv = b1[nt*16 + n15];
      #pragma unroll
      for (int reg = 0; reg < 4; ++reg)
        Z[quad*4 + reg][nt*16 + n15] = fmaxf(acc[nt][reg] + bv, 0.f);
    }

    // read z back in A-frag layout, convert, second matmul
    #pragma unroll
    for (int ks = 0; ks < 4; ++ks){
      float4 z0 = *(const float4*)&Z[n15][ks*32 + quad*8 + 0];
      float4 z1 = *(const float4*)&Z[n15][ks*32 + quad*8 + 4];
      float av[8] = {z0.x,z0.y,z0.z,z0.w,z1.x,z1.y,z1.z,z1.w};
      conv8(av, ah[ks], al[ks]);
    }

    floatx4 acc2[8] = {};
    mfma3(acc2, ah, al, h2, l2);

    // out = acc2 + b2 -> stats + LDS
    #pragma unroll
    for (int nt = 0; nt < 8; ++nt){
      float bv = b2[nt*16 + n15];
      #pragma unroll
      for (int reg = 0; reg < 4; ++reg){
        float v = acc2[nt][reg] + bv;
        s0[nt] += v;
        s1[nt] += v*v;
        Z[quad*4 + reg][nt*16 + n15] = v;
      }
    }

    // coalesced readback + store: 8 lanes cover one full 128B row segment
    #pragma unroll
    for (int ii = 0; ii < 2; ++ii){
      int row = (l >> 3) + 8*ii;
      float* orow = x + (size_t)(g*64 + w*16 + row)*H;
      #pragma unroll
      for (int jj = 0; jj < 4; ++jj){
        int c4 = ((l & 7) + 8*jj)*4;
        *(float4*)(orow + c4) = *(const float4*)&Z[row][c4];
      }
    }
  }

  // stats reduce: cross-quad shuffle, cross-wave via LDS (zb dead), per-block partial row
  __syncthreads();
  double* red = (double*)&zb[0][0][0];
  #pragma unroll
  for (int nt = 0; nt < 8; ++nt){
    float a = s0[nt], b = s1[nt];
    a += __shfl_xor(a, 16, 64); b += __shfl_xor(b, 16, 64);
    a += __shfl_xor(a, 32, 64); b += __shfl_xor(b, 32, 64);
    if (quad == 0){
      int col = nt*16 + n15;
      red[(size_t)(w*2+0)*H + col] = (double)a;
      red[(size_t)(w*2+1)*H + col] = (double)b;
    }
  }
  __syncthreads();
  if (tid < H){
    int col = tid;
    double a = red[0*H+col] + red[2*H+col] + red[4*H+col] + red[6*H+col];
    double b = red[1*H+col] + red[3*H+col] + red[5*H+col] + red[7*H+col];
    part[(size_t)(blockIdx.x*2+0)*H + col] = a;
    part[(size_t)(blockIdx.x*2+1)*H + col] = b;
  }
}

// ---------------- fused self-matmul + combine: h = combine(BN(hmid), h@selfW+b, r2, agg2), in-place ----------------

__global__ __launch_bounds__(256, 2) void k_selfcombine(
    float* __restrict__ h, int rows,
    const short* __restrict__ whiS, const short* __restrict__ wloS, const float* __restrict__ biasS,
    const float* __restrict__ hmid, const float* __restrict__ r2,
    const float* __restrict__ agg2, const float* __restrict__ muinv,
    const float* __restrict__ bng, const float* __restrict__ bnb,
    const int* __restrict__ nids)
{
  __shared__ float zb[4][16][ZPAD];
  int tid = threadIdx.x;
  int w = tid >> 6, l = tid & 63;
  int quad = l >> 4, n15 = l & 15;
  const short* hp = whiS + l*8;
  const short* lp = wloS + l*8;
  float (*Z)[ZPAD] = zb[w];

  int ngroups = rows >> 6;
  for (int g = blockIdx.x; g < ngroups; g += gridDim.x){
    const float* ap = h + (size_t)(g*64 + w*16 + n15)*H + quad*8;
    short8 ah[4], al[4];
    #pragma unroll
    for (int ks = 0; ks < 4; ++ks){
      float4 a0 = *(const float4*)(ap + ks*32 + 0);
      float4 a1 = *(const float4*)(ap + ks*32 + 4);
      float av[8] = {a0.x,a0.y,a0.z,a0.w,a1.x,a1.y,a1.z,a1.w};
      conv8(av, ah[ks], al[ks]);
    }

    floatx4 acc[8] = {};
    mfma3(acc, ah, al, hp, lp);

    // r1 = acc + biasS -> LDS (C-layout)
    #pragma unroll
    for (int nt = 0; nt < 8; ++nt){
      float bv = biasS[nt*16 + n15];
      #pragma unroll
      for (int reg = 0; reg < 4; ++reg)
        Z[quad*4 + reg][nt*16 + n15] = acc[nt][reg] + bv;
    }

    // coalesced combine epilogue
    #pragma unroll
    for (int ii = 0; ii < 2; ++ii){
      int row = (l >> 3) + 8*ii;
      int r = g*64 + w*16 + row;
      int nid = nids[r];
      float vf = (nid >= 0) ? 1.f : 0.f;
      int cid = (nid < 0) ? 0 : nid;
      bool isroot = (r % KK) == 0;
      int rs = r / KK;
      const float* hmrow = hmid + (size_t)r*H;
      const float* r2row = r2 + (size_t)rs*H;
      const float* hirow = agg2 + (size_t)cid*H;
      float* orow = h + (size_t)r*H;
      #pragma unroll
      for (int jj = 0; jj < 4; ++jj){
        int c4 = ((l & 7) + 8*jj)*4;
        float4 hm = *(const float4*)(hmrow + c4);
        float4 mu = *(const float4*)(muinv + c4);
        float4 iv = *(const float4*)(muinv + H + c4);
        float4 g4 = *(const float4*)(bng + c4);
        float4 b4 = *(const float4*)(bnb + c4);
        float4 h1;
        h1.x = ((hm.x-mu.x)*iv.x*g4.x + b4.x) * vf;
        h1.y = ((hm.y-mu.y)*iv.y*g4.y + b4.y) * vf;
        h1.z = ((hm.z-mu.z)*iv.z*g4.z + b4.z) * vf;
        h1.w = ((hm.w-mu.w)*iv.w*g4.w + b4.w) * vf;
        float4 o;
        if (isroot){
          float4 hi = *(const float4*)(hirow + c4);
          o.x = h1.x + hi.x*vf; o.y = h1.y + hi.y*vf;
          o.z = h1.z + hi.z*vf; o.w = h1.w + hi.w*vf;
        } else {
          float4 r1 = *(const float4*)&Z[row][c4];
          float4 rr = *(const float4*)(r2row + c4);
          o.x = h1.x + r1.x + rr.x; o.y = h1.y + r1.y + rr.y;
          o.z = h1.z + r1.z + rr.z; o.w = h1.w + r1.w + rr.w;
        }
        o.x = fmaxf(o.x,0.f)*vf; o.y = fmaxf(o.y,0.f)*vf;
        o.z = fmaxf(o.z,0.f)*vf; o.w = fmaxf(o.w,0.f)*vf;
        *(float4*)(orow + c4) = o;
      }
    }
  }
}

// ---------------- BatchNorm (two-stage, no atomics; parallel final reduce) ----------------

__global__ void k_bnstats_p(const float* __restrict__ x, int rows, double* __restrict__ part){
  int g = blockIdx.x*256 + threadIdx.x;
  int c = g & (H-1);
  int s = g >> 7;
  int stride = (gridDim.x*256) >> 7;
  double a = 0.0, b = 0.0;
  for (int r = s; r < rows; r += stride){
    float v = x[(size_t)r*H + c];
    a += v; b += (double)v*(double)v;
  }
  part[(size_t)(s*2+0)*H + c] = a;
  part[(size_t)(s*2+1)*H + c] = b;
}

__global__ void k_bnfin_par(const double* __restrict__ part, int nstreams, int rows,
                            float* __restrict__ muinv){
  __shared__ double sh0[256], sh1[256];
  int c = blockIdx.x;
  int tid = threadIdx.x;
  double a = 0.0, b = 0.0;
  for (int s = tid; s < nstreams; s += 256){
    a += part[(size_t)(s*2+0)*H + c];
    b += part[(size_t)(s*2+1)*H + c];
  }
  sh0[tid] = a; sh1[tid] = b;
  __syncthreads();
  for (int ofs = 128; ofs > 0; ofs >>= 1){
    if (tid < ofs){ sh0[tid] += sh0[tid+ofs]; sh1[tid] += sh1[tid+ofs]; }
    __syncthreads();
  }
  if (tid == 0){
    double mu = sh0[0] / (double)rows;
    double var = sh1[0] / (double)rows - mu*mu;
    muinv[c]   = (float)mu;
    muinv[H+c] = (float)(1.0 / sqrt(var + (double)BN_EPS));
  }
}

__global__ void k_bnapply(float* __restrict__ x, const float* __restrict__ muinv,
                          const float* __restrict__ g, const float* __restrict__ b, int rows){
  int idx = blockIdx.x*256 + threadIdx.x;
  if (idx >= rows*H4) return;
  int r = idx >> 5; int c = (idx & 31) << 2;
  float4 v  = *(const float4*)(x + (size_t)r*H + c);
  float4 mu = *(const float4*)(muinv + c);
  float4 iv = *(const float4*)(muinv + H + c);
  float4 gg = *(const float4*)(g + c);
  float4 bb = *(const float4*)(b + c);
  v.x = (v.x-mu.x)*iv.x*gg.x + bb.x;
  v.y = (v.y-mu.y)*iv.y*gg.y + bb.y;
  v.z = (v.z-mu.z)*iv.z*gg.z + bb.z;
  v.w = (v.w-mu.w)*iv.w*gg.w + bb.w;
  *(float4*)(x + (size_t)r*H + c) = v;
}

// ---------------- readout ----------------

__global__ void k_hsub(float* __restrict__ hsub, const float* __restrict__ h){
  int idx = blockIdx.x*256 + threadIdx.x;
  if (idx >= SS*H4) return;
  int s = idx >> 5; int c = (idx & 31) << 2;
  float4 acc = make_float4(0.f,0.f,0.f,0.f);
  const float* base = h + (size_t)s*KK*H + c;
  #pragma unroll
  for (int k = 0; k < KK; ++k){
    float4 v = *(const float4*)(base + (size_t)k*H);
    acc.x += v.x; acc.y += v.y; acc.z += v.z; acc.w += v.w;
  }
  *(float4*)(hsub + (size_t)s*H + c) = acc;
}

__global__ void k_poolw(float* __restrict__ poolw, const float* __restrict__ lp,
                        const float* __restrict__ alpha){
  int n = blockIdx.x*256 + threadIdx.x;
  if (n >= NN) return;
  float a = alpha[0];
  float s0 = -a*lp[n*MSUB+0], s1 = -a*lp[n*MSUB+1], s2 = -a*lp[n*MSUB+2], s3 = -a*lp[n*MSUB+3];
  float m = fmaxf(fmaxf(s0,s1), fmaxf(s2,s3));
  float e0 = expf(s0-m), e1 = expf(s1-m), e2 = expf(s2-m), e3 = expf(s3-m);
  float sum = e0+e1+e2+e3;
  poolw[n*MSUB+0] = e0/sum; poolw[n*MSUB+1] = e1/sum;
  poolw[n*MSUB+2] = e2/sum; poolw[n*MSUB+3] = e3/sum;
}

__global__ void k_nodeemb(float* __restrict__ nemb, const float* __restrict__ hsub,
                          const float* __restrict__ poolw){
  int idx = blockIdx.x*256 + threadIdx.x;
  if (idx >= NN*H4) return;
  int n = idx >> 5; int c = (idx & 31) << 2;
  float w0 = poolw[n*MSUB+0], w1 = poolw[n*MSUB+1], w2 = poolw[n*MSUB+2], w3 = poolw[n*MSUB+3];
  const float* base = hsub + (size_t)n*MSUB*H + c;
  float4 v0 = *(const float4*)(base + 0*H);
  float4 v1 = *(const float4*)(base + 1*H);
  float4 v2 = *(const float4*)(base + 2*H);
  float4 v3 = *(const float4*)(base + 3*H);
  float4 o;
  o.x = w0*v0.x + w1*v1.x + w2*v2.x + w3*v3.x;
  o.y = w0*v0.y + w1*v1.y + w2*v2.y + w3*v3.y;
  o.z = w0*v0.z + w1*v1.z + w2*v2.z + w3*v3.z;
  o.w = w0*v0.w + w1*v1.w + w2*v2.w + w3*v3.w;
  *(float4*)(nemb + (size_t)n*H + c) = o;
}

__global__ void k_out(float* __restrict__ out, const float* __restrict__ nemb,
                      const float* __restrict__ muinv, const float* __restrict__ g,
                      const float* __restrict__ b){
  int idx = blockIdx.x*256 + threadIdx.x;
  if (idx >= NBATCH*H) return;
  int bi = idx >> 7; int c = idx & (H-1);
  float mu = muinv[c], iv = muinv[H+c], gg = g[c], bb = b[c];
  float acc = 0.f;
  const float* base = nemb + (size_t)bi*(NN/NBATCH)*H + c;
  for (int i = 0; i < NN/NBATCH; ++i)
    acc += (base[(size_t)i*H] - mu)*iv*gg + bb;
  out[idx] = acc;
}

// ---------------- launch ----------------

extern "C" void kernel_launch(void* const* d_in, const int* in_sizes, int n_in,
                              void* d_out, int out_size, void* d_ws, size_t ws_size,
                              hipStream_t stream) {
  const int*   x_tok      = (const int*)  d_in[0];
  const int*   dist       = (const int*)  d_in[1];
  const int*   node_ids   = (const int*)  d_in[2];
  const int*   sub_batch  = (const int*)  d_in[4];
  const int*   rfi        = (const int*)  d_in[5];
  const int*   intra_ei   = (const int*)  d_in[6];
  const int*   edge_index = (const int*)  d_in[7];
  const float* lp         = (const float*)d_in[9];
  const float* ea_flat    = (const float*)d_in[10];
  const float* edge_attr  = (const float*)d_in[11];
  const float* atom_emb   = (const float*)d_in[12];
  const float* dist_emb   = (const float*)d_in[13];
  const float* logp_w     = (const float*)d_in[14];
  const float* logp_b     = (const float*)d_in[15];
  const float* intra_W1   = (const float*)d_in[16];
  const float* intra_b1   = (const float*)d_in[17];
  const float* intra_W2   = (const float*)d_in[18];
  const float* intra_b2   = (const float*)d_in[19];
  const float* intra_bn_g = (const float*)d_in[20];
  const float* intra_bn_b = (const float*)d_in[21];
  const float* self_W     = (const float*)d_in[22];
  const float* self_b     = (const float*)d_in[23];
  const float* root_W     = (const float*)d_in[24];
  const float* root_b     = (const float*)d_in[25];
  const float* inter_W1   = (const float*)d_in[26];
  const float* inter_b1   = (const float*)d_in[27];
  const float* inter_W2   = (const float*)d_in[28];
  const float* inter_b2   = (const float*)d_in[29];
  const float* inter_bn_g = (const float*)d_in[30];
  const float* inter_bn_b = (const float*)d_in[31];
  const float* ro_bn_g    = (const float*)d_in[32];
  const float* ro_bn_b    = (const float*)d_in[33];
  const float* alpha_pool = (const float*)d_in[34];
  const float* alpha_inter= (const float*)d_in[35];

  const int* isrc = intra_ei;
  const int* idst = intra_ei + EINTRA;
  const int* esrc = edge_index;
  const int* edst = edge_index + EINTER;

  float* out = (float*)d_out;

  char* ws = (char*)d_ws;
  size_t off = 0;
  auto nxt = [&](size_t bytes) -> void* {
    void* p = ws + off;
    off += (bytes + 255) & ~(size_t)255;
    return p;
  };
  const int G_MM_F = 1024;                      // fused FF kernels: 4 blocks/CU resident
  const int G_MM_S = (SS + 63)/64;              // 157
  const int G_MM_N = (NN + 63)/64;              // 40
  const int G_BN_S = 32;                        // small-BN stat blocks -> 64 streams

  float*  h      = (float*) nxt((size_t)FF*H*4);
  float*  hmid   = (float*) nxt((size_t)FF*H*4);
  float*  r2     = (float*) nxt((size_t)SS*H*4);
  float*  canon  = (float*) nxt((size_t)NN*H*4);
  float*  agg2   = (float*) nxt((size_t)NN*H*4);
  float*  tbufN  = (float*) nxt((size_t)NN*H*4);
  float*  hsub   = (float*) nxt((size_t)SS*H*4);
  float*  nemb   = (float*) nxt((size_t)NN*H*4);
  float*  htw    = (float*) nxt((size_t)SS*4);
  float*  poolw  = (float*) nxt((size_t)NN*MSUB*4);
  double* statsA = (double*)nxt((size_t)G_MM_F*2*H*8);       // per-block partials (2 MB)
  double* statsB = (double*)nxt((size_t)(G_BN_S*2)*2*H*8);   // 64-stream partials
  float*  muinvA = (float*) nxt((size_t)2*H*4);
  float*  muinvB = (float*) nxt((size_t)2*H*4);
  short*  whiG   = (short*) nxt((size_t)24*WF_SHORTS*2);     // hi-split frag-major W (768 KB)
  short*  wloG   = (short*) nxt((size_t)24*WF_SHORTS*2);     // lo-split frag-major W (768 KB)
  int*    icnt   = (int*)   nxt((size_t)FF*4);
  int*    ibeid  = (int*)   nxt((size_t)FF*CAP_I*4);
  int*    ecnt   = (int*)   nxt((size_t)NN*4);
  int*    ebeid  = (int*)   nxt((size_t)NN*CAP_E*4);
  int*    irow   = (int*)   nxt((size_t)FF*4);
  int*    erow   = (int*)   nxt((size_t)NN*4);
  int2*   ies    = (int2*)  nxt((size_t)EINTRA*8);
  int2*   ees    = (int2*)  nxt((size_t)EINTER*8);
  int*    gcnt   = (int*)   nxt((size_t)2*4);
  (void)ws_size; (void)n_in; (void)in_sizes; (void)out_size; (void)sub_batch;

  const int G_FH4 = FF*H4/256;
  const int G_SH4 = SS*H4/256;
  const int G_NH4 = (NN*H4 + 255)/256;
  const int G_N   = (NN + 255)/256;
  const int G_F   = (FF + 255)/256;

  // zero counters (ws poisoned before every call)
  k_zeroi<<<G_F, 256, 0, stream>>>(icnt, FF);
  k_zeroi<<<G_N, 256, 0, stream>>>(ecnt, NN);
  k_zeroi<<<1, 256, 0, stream>>>(gcnt, 2);

  // W split prep (once)
  k_wprep<<<24*8, 256, 0, stream>>>(intra_W1, intra_W2, self_W, root_W,
                                    inter_W1, inter_W2, whiG, wloG);

  // CSR buckets -> packed {e,src} segments
  k_bucket<<<(EINTRA+255)/256, 256, 0, stream>>>(idst, EINTRA, icnt, ibeid, CAP_I);
  k_bucket<<<(EINTER+255)/256, 256, 0, stream>>>(edst, EINTER, ecnt, ebeid, CAP_E);
  k_scan<<<G_F, 256, 0, stream>>>(icnt, FF, CAP_I, irow, gcnt);
  k_scan<<<G_N, 256, 0, stream>>>(ecnt, NN, CAP_E, erow, gcnt+1);
  k_csr_fill<<<G_F, 256, 0, stream>>>(icnt, irow, ibeid, isrc, FF, CAP_I, ies);
  k_csr_fill<<<G_N, 256, 0, stream>>>(ecnt, erow, ebeid, esrc, NN, CAP_E, ees);

  // input encoding + HT weights
  k_encode<<<G_FH4, 256, 0, stream>>>(h, x_tok, dist, node_ids, sub_batch, lp,
                                      atom_emb, dist_emb, logp_w, logp_b);
  k_htw<<<G_N, 256, 0, stream>>>(node_ids, rfi, lp, alpha_inter, htw);

  for (int l = 0; l < NLAYER; ++l){
    const short* hi_iW1 = whiG + (size_t)(l*6+0)*WF_SHORTS;
    const short* hi_iW2 = whiG + (size_t)(l*6+1)*WF_SHORTS;
    const short* hi_sW  = whiG + (size_t)(l*6+2)*WF_SHORTS;
    const short* hi_rW  = whiG + (size_t)(l*6+3)*WF_SHORTS;
    const short* hi_nW1 = whiG + (size_t)(l*6+4)*WF_SHORTS;
    const short* hi_nW2 = whiG + (size_t)(l*6+5)*WF_SHORTS;
    const short* lo_iW1 = wloG + (size_t)(l*6+0)*WF_SHORTS;
    const short* lo_iW2 = wloG + (size_t)(l*6+1)*WF_SHORTS;
    const short* lo_sW  = wloG + (size_t)(l*6+2)*WF_SHORTS;
    const short* lo_rW  = wloG + (size_t)(l*6+3)*WF_SHORTS;
    const short* lo_nW1 = wloG + (size_t)(l*6+4)*WF_SHORTS;
    const short* lo_nW2 = wloG + (size_t)(l*6+5)*WF_SHORTS;

    // intra GINE stage1 (CSR gather) -> hmid
    k_gine_gather2<<<G_FH4, 256, 0, stream>>>(hmid, h, ea_flat, icnt, irow, ies, FF, CAP_I);
    // fused MLP in-place on hmid, + BN-stats partials
    k_mlp_fused<<<G_MM_F, 256, 0, stream>>>(hmid, FF,
                                            hi_iW1, lo_iW1, intra_b1 + (size_t)l*H,
                                            hi_iW2, lo_iW2, intra_b2 + (size_t)l*H, statsA);
    k_bnfin_par<<<H, 256, 0, stream>>>(statsA, G_MM_F, FF, muinvA);

    // HT root gather to canonical nodes
    k_canon<<<G_NH4, 256, 0, stream>>>(canon, h, htw, rfi);
    // r2[s] = h[rfi[s]] @ root_W + root_b
    k_mm_mfma<<<G_MM_S, 256, 0, stream>>>(h, r2, SS, hi_rW, lo_rW,
                                          root_b + (size_t)l*H, 0, rfi);

    // inter GINE (CSR gather)
    k_gine_gather2<<<G_NH4, 256, 0, stream>>>(agg2, canon, edge_attr, ecnt, erow, ees, NN, CAP_E);
    k_mm_mfma<<<G_MM_N, 256, 0, stream>>>(agg2, tbufN, NN, hi_nW1, lo_nW1,
                                          inter_b1 + (size_t)l*H, 1, nullptr);
    k_mm_mfma<<<G_MM_N, 256, 0, stream>>>(tbufN, agg2, NN, hi_nW2, lo_nW2,
                                          inter_b2 + (size_t)l*H, 0, nullptr);
    k_bnstats_p<<<G_BN_S, 256, 0, stream>>>(agg2, NN, statsB);
    k_bnfin_par<<<H, 256, 0, stream>>>(statsB, G_BN_S*2, NN, muinvB);
    k_bnapply<<<G_NH4, 256, 0, stream>>>(agg2, muinvB, inter_bn_g + (size_t)l*H,
                                         inter_bn_b + (size_t)l*H, NN);

    // fused self-matmul + combine, in-place on h
    k_selfcombine<<<G_MM_F, 256, 0, stream>>>(h, FF, hi_sW, lo_sW,
                                              self_b + (size_t)l*H, hmid, r2, agg2,
                                              muinvA, intra_bn_g + (size_t)l*H,
                                              intra_bn_b + (size_t)l*H, node_ids);
  }

  // readout
  k_hsub<<<G_SH4, 256, 0, stream>>>(hsub, h);
  k_poolw<<<G_N, 256, 0, stream>>>(poolw, lp, alpha_pool);
  k_nodeemb<<<G_NH4, 256, 0, stream>>>(nemb, hsub, poolw);
  k_bnstats_p<<<G_BN_S, 256, 0, stream>>>(nemb, NN, statsB);
  k_bnfin_par<<<H, 256, 0, stream>>>(statsB, G_BN_S*2, NN, muinvB);
  k_out<<<(NBATCH*H+255)/256, 256, 0, stream>>>(out, nemb, muinvB, ro_bn_g, ro_bn_b);
}

// Round 8
// 2066.007 us; speedup vs baseline: 1.4233x; 1.4233x over previous
//
#include <hip/hip_runtime.h>
#include <math.h>

#define H 128
#define H4 (H/4)
#define KK 12
#define MSUB 4
#define FF 120000
#define SS 10000
#define NN 2500
#define NBATCH 50
#define NLAYER 4
#define EINTRA 240000
#define EINTER 40000
#define HH (H*H)
#define BN_EPS 1e-5f
#define CAP_I 32
#define CAP_E 96
#define WF_SHORTS 16384   // per matrix per split: 128*128
#define ZP 68             // half-width z-tile pad (272B rows, 16B aligned)

typedef short short8 __attribute__((ext_vector_type(8)));
typedef float floatx4 __attribute__((ext_vector_type(4)));

__device__ __forceinline__ unsigned short f2bf_rne(float x){
  unsigned u = __float_as_uint(x);
  unsigned r = u + 0x7FFFu + ((u >> 16) & 1u);
  return (unsigned short)(r >> 16);
}

// ---------------- small helpers ----------------

__global__ void k_zeroi(int* __restrict__ p, int n){
  int i = blockIdx.x*256 + threadIdx.x;
  if (i < n) p[i] = 0;
}

// ---------------- CSR bucket build ----------------

__global__ void k_bucket(const int* __restrict__ dst, int E, int* __restrict__ cnt,
                         int* __restrict__ beid, int cap){
  int e = blockIdx.x*256 + threadIdx.x;
  if (e >= E) return;
  int d = dst[e];
  int p = atomicAdd(&cnt[d], 1);
  if (p < cap) beid[(size_t)d*cap + p] = e;
}

__global__ void k_scan(const int* __restrict__ cnt, int rows, int cap,
                       int* __restrict__ rowptr, int* __restrict__ gcount){
  __shared__ int sdata[256];
  __shared__ int sbase;
  int tid = threadIdx.x;
  int r = blockIdx.x*256 + tid;
  int v = 0;
  if (r < rows){ v = cnt[r]; if (v > cap) v = cap; }
  sdata[tid] = v;
  __syncthreads();
  for (int ofs = 1; ofs < 256; ofs <<= 1){
    int t = (tid >= ofs) ? sdata[tid-ofs] : 0;
    __syncthreads();
    sdata[tid] += t;
    __syncthreads();
  }
  if (tid == 255) sbase = atomicAdd(gcount, sdata[255]);
  __syncthreads();
  if (r < rows) rowptr[r] = sbase + sdata[tid] - v;
}

__global__ void k_csr_fill(const int* __restrict__ cnt, const int* __restrict__ rowptr,
                           const int* __restrict__ beid, const int* __restrict__ src,
                           int rows, int cap, int2* __restrict__ es){
  int f = blockIdx.x*256 + threadIdx.x;
  if (f >= rows) return;
  int n = cnt[f]; if (n > cap) n = cap;
  int base = rowptr[f];
  const int* bl = beid + (size_t)f*cap;
  for (int i = 0; i < n; ++i){
    int e = bl[i];
    es[base + i] = make_int2(e, src[e]);
  }
}

// ---------------- W split prep (frag-major hi+lo), once ----------------
// idx per matrix: (ks*8+nt)*512 + lane*8 + j; 24 mats: layer*6 + {0=iW1,1=iW2,2=selfW,3=rootW,4=inW1,5=inW2}

__global__ void k_wprep(const float* __restrict__ iW1, const float* __restrict__ iW2,
                        const float* __restrict__ sW,  const float* __restrict__ rW,
                        const float* __restrict__ nW1, const float* __restrict__ nW2,
                        short* __restrict__ whiG, short* __restrict__ wloG){
  int mat = blockIdx.x >> 3;                      // 24 matrices, 8 blocks each
  int t = (blockIdx.x & 7)*256 + threadIdx.x;     // 0..2047 : (ks,nt,lane)
  int l = t & 63, nt = (t >> 6) & 7, ks = t >> 9;
  int layer = mat / 6, which = mat % 6;
  const float* W;
  switch (which){
    case 0: W = iW1; break; case 1: W = iW2; break; case 2: W = sW; break;
    case 3: W = rW;  break; case 4: W = nW1; break; default: W = nW2; break;
  }
  W += (size_t)layer*HH;
  short* oh = whiG + (size_t)mat*WF_SHORTS;
  short* ol = wloG + (size_t)mat*WF_SHORTS;
  int quad = l >> 4, n15 = l & 15;
  #pragma unroll
  for (int j = 0; j < 8; ++j){
    int k = ks*32 + quad*8 + j;
    int n = nt*16 + n15;
    float v = W[(size_t)k*H + n];
    unsigned short hb = f2bf_rne(v);
    float hf = __uint_as_float((unsigned)hb << 16);
    int idx = (ks*8 + nt)*512 + l*8 + j;
    oh[idx] = (short)hb;
    ol[idx] = (short)f2bf_rne(v - hf);
  }
}

// ---------------- input encoding ----------------

__global__ void k_encode(float* __restrict__ h, const int* __restrict__ xtok,
                         const int* __restrict__ dist, const int* __restrict__ nids,
                         const int* __restrict__ subb, const float* __restrict__ lp,
                         const float* __restrict__ aemb, const float* __restrict__ demb,
                         const float* __restrict__ lw, const float* __restrict__ lb){
  int idx = blockIdx.x*256 + threadIdx.x;
  if (idx >= FF*H4) return;
  int f = idx >> 5; int c = (idx & 31) << 2;
  float vf = (nids[f] >= 0) ? 1.f : 0.f;
  float l = lp[subb[f]];
  float4 a = *(const float4*)(aemb + (size_t)xtok[f]*H + c);
  float4 d = *(const float4*)(demb + (size_t)dist[f]*H + c);
  float4 w = *(const float4*)(lw + c);
  float4 b = *(const float4*)(lb + c);
  float4 o;
  o.x = (a.x + d.x + fmaxf(fmaf(l, w.x, b.x), 0.f)) * vf;
  o.y = (a.y + d.y + fmaxf(fmaf(l, w.y, b.y), 0.f)) * vf;
  o.z = (a.z + d.z + fmaxf(fmaf(l, w.z, b.z), 0.f)) * vf;
  o.w = (a.w + d.w + fmaxf(fmaf(l, w.w, b.w), 0.f)) * vf;
  *(float4*)(h + (size_t)f*H + c) = o;
}

// ---------------- HT weights ----------------

__global__ void k_htw(const int* __restrict__ nids, const int* __restrict__ rfi,
                      const float* __restrict__ lp, const float* __restrict__ alpha,
                      float* __restrict__ htw){
  int n = blockIdx.x*256 + threadIdx.x;
  if (n >= NN) return;
  float a = alpha[0];
  float w[MSUB]; float sum = 0.f;
  #pragma unroll
  for (int m = 0; m < MSUB; ++m){
    int s = n*MSUB + m;
    int rid = nids[rfi[s]];
    float wm = (rid >= 0) ? expf(-a*lp[s]) : 0.f;
    w[m] = wm; sum += wm;
  }
  float inv = 1.f / (sum + 1e-16f);
  #pragma unroll
  for (int m = 0; m < MSUB; ++m) htw[n*MSUB + m] = w[m]*inv;
}

// ---------------- GINE gather (CSR form) ----------------

__global__ void k_gine_gather2(float* __restrict__ outa, const float* __restrict__ x,
                               const float* __restrict__ ea, const int* __restrict__ cnt,
                               const int* __restrict__ rowptr, const int2* __restrict__ es,
                               int rows, int cap){
  int idx = blockIdx.x*256 + threadIdx.x;
  if (idx >= rows*H4) return;
  int f = idx >> 5; int c = (idx & 31) << 2;
  float4 acc = *(const float4*)(x + (size_t)f*H + c);
  int n = cnt[f]; if (n > cap) n = cap;
  const int2* p = es + rowptr[f];
  int i = 0;
  for (; i + 2 <= n; i += 2){
    int2 e0 = p[i];
    int2 e1 = p[i+1];
    float4 x0 = *(const float4*)(x + (size_t)e0.y*H + c);
    float4 a0 = *(const float4*)(ea + (size_t)e0.x*H + c);
    float4 x1 = *(const float4*)(x + (size_t)e1.y*H + c);
    float4 a1 = *(const float4*)(ea + (size_t)e1.x*H + c);
    acc.x += fmaxf(x0.x + a0.x, 0.f) + fmaxf(x1.x + a1.x, 0.f);
    acc.y += fmaxf(x0.y + a0.y, 0.f) + fmaxf(x1.y + a1.y, 0.f);
    acc.z += fmaxf(x0.z + a0.z, 0.f) + fmaxf(x1.z + a1.z, 0.f);
    acc.w += fmaxf(x0.w + a0.w, 0.f) + fmaxf(x1.w + a1.w, 0.f);
  }
  if (i < n){
    int2 e0 = p[i];
    float4 x0 = *(const float4*)(x + (size_t)e0.y*H + c);
    float4 a0 = *(const float4*)(ea + (size_t)e0.x*H + c);
    acc.x += fmaxf(x0.x + a0.x, 0.f);
    acc.y += fmaxf(x0.y + a0.y, 0.f);
    acc.z += fmaxf(x0.z + a0.z, 0.f);
    acc.w += fmaxf(x0.w + a0.w, 0.f);
  }
  *(float4*)(outa + (size_t)f*H + c) = acc;
}

// ---------------- HT root gather ----------------

__global__ void k_canon(float* __restrict__ canon, const float* __restrict__ h,
                        const float* __restrict__ htw, const int* __restrict__ rfi){
  int idx = blockIdx.x*256 + threadIdx.x;
  if (idx >= NN*H4) return;
  int n = idx >> 5; int c = (idx & 31) << 2;
  float4 acc = make_float4(0.f,0.f,0.f,0.f);
  #pragma unroll
  for (int m = 0; m < MSUB; ++m){
    int s = n*MSUB + m;
    float w = htw[s];
    const float* p = h + (size_t)rfi[s]*H + c;
    acc.x += w*p[0]; acc.y += w*p[1]; acc.z += w*p[2]; acc.w += w*p[3];
  }
  *(float4*)(canon + (size_t)n*H + c) = acc;
}

// ---------------- MFMA helpers ----------------

__device__ __forceinline__ void conv8(const float* av, short8& ah, short8& al){
  #pragma unroll
  for (int j = 0; j < 8; ++j){
    unsigned short hb = f2bf_rne(av[j]);
    float hf = __uint_as_float((unsigned)hb << 16);
    ah[j] = (short)hb;
    al[j] = (short)f2bf_rne(av[j] - hf);
  }
}

// ---------------- split-bf16 MFMA matmul ----------------
// hi-split W copied whiG->LDS (32 KB, straight bf16 copy); lo-split from global (L2 broadcast).
// Epilogue: two half-width passes through per-wave LDS tile [16][ZP] -> coalesced float4 stores.
// LDS = 32768 + 17408 = 50176 B -> 3 blocks/CU at 128 VGPR.

__global__ __launch_bounds__(256, 2) void k_mm_mfma(
    const float* __restrict__ in, float* __restrict__ out, int rows,
    const short* __restrict__ whiG, const short* __restrict__ wlo,
    const float* __restrict__ bias, int do_relu, const int* __restrict__ gather)
{
  __shared__ __align__(16) short whi[WF_SHORTS];   // 32 KB
  __shared__ __align__(16) float zb[4][16][ZP];    // 17 KB
  int tid = threadIdx.x;
  int w = tid >> 6, l = tid & 63;
  int quad = l >> 4, n15 = l & 15;

  #pragma unroll
  for (int i = 0; i < 8; ++i)
    *(short8*)&whi[(tid*8 + i*2048)*1] = *(const short8*)&whiG[(tid + i*256)*8];
  __syncthreads();

  const short* hp = whi + l*8;
  const short* lp = wlo + l*8;
  float (*Z)[ZP] = zb[w];

  int ngroups = (rows + 63) >> 6;
  for (int g = blockIdx.x; g < ngroups; g += gridDim.x){
    int rload = g*64 + w*16 + n15;
    bool okload = rload < rows;
    int ir = okload ? (gather ? gather[rload] : rload) : 0;
    const float* ap = in + (size_t)ir*H + quad*8;

    short8 ah[4], al[4];
    #pragma unroll
    for (int ks = 0; ks < 4; ++ks){
      float4 a0 = okload ? *(const float4*)(ap + ks*32 + 0) : make_float4(0.f,0.f,0.f,0.f);
      float4 a1 = okload ? *(const float4*)(ap + ks*32 + 4) : make_float4(0.f,0.f,0.f,0.f);
      float av[8] = {a0.x,a0.y,a0.z,a0.w,a1.x,a1.y,a1.z,a1.w};
      conv8(av, ah[ks], al[ks]);
    }

    floatx4 acc[8] = {};
    #pragma unroll
    for (int ks = 0; ks < 4; ++ks){
      #pragma unroll
      for (int nt = 0; nt < 8; ++nt){
        short8 bh = *(const short8*)(hp + (ks*8 + nt)*512);
        short8 bl = *(const short8*)(lp + (ks*8 + nt)*512);
        acc[nt] = __builtin_amdgcn_mfma_f32_16x16x32_bf16(ah[ks], bh, acc[nt], 0, 0, 0);
        acc[nt] = __builtin_amdgcn_mfma_f32_16x16x32_bf16(al[ks], bh, acc[nt], 0, 0, 0);
        acc[nt] = __builtin_amdgcn_mfma_f32_16x16x32_bf16(ah[ks], bl, acc[nt], 0, 0, 0);
      }
    }

    int rbase = g*64 + w*16;
    #pragma unroll
    for (int half = 0; half < 2; ++half){
      #pragma unroll
      for (int ntl = 0; ntl < 4; ++ntl){
        int nt = half*4 + ntl;
        float bv = bias[nt*16 + n15];
        #pragma unroll
        for (int reg = 0; reg < 4; ++reg){
          float v = acc[nt][reg] + bv;
          if (do_relu) v = fmaxf(v, 0.f);
          Z[quad*4 + reg][ntl*16 + n15] = v;
        }
      }
      // wave-local readback (no barrier needed), coalesced 128B-line stores
      #pragma unroll
      for (int ii = 0; ii < 2; ++ii){
        int row = (l >> 3) + 8*ii;
        int r = rbase + row;
        if (r < rows){
          float* orow = out + (size_t)r*H + half*64;
          #pragma unroll
          for (int jj = 0; jj < 2; ++jj){
            int c4 = ((l & 7) + 8*jj)*4;
            *(float4*)(orow + c4) = *(const float4*)&Z[row][c4];
          }
        }
      }
    }
  }
}

// ---------------- same matmul + fused BN-stats (per-block partials, no atomics) ----------------

__global__ __launch_bounds__(256, 2) void k_mm_mfma_stats(
    const float* __restrict__ in, float* __restrict__ out, int rows,
    const short* __restrict__ whiG, const short* __restrict__ wlo,
    const float* __restrict__ bias, double* __restrict__ part)
{
  __shared__ __align__(16) short whi[WF_SHORTS];
  __shared__ __align__(16) float zb[4][16][ZP];
  int tid = threadIdx.x;
  int w = tid >> 6, l = tid & 63;
  int quad = l >> 4, n15 = l & 15;

  #pragma unroll
  for (int i = 0; i < 8; ++i)
    *(short8*)&whi[(tid*8 + i*2048)*1] = *(const short8*)&whiG[(tid + i*256)*8];
  __syncthreads();

  const short* hp = whi + l*8;
  const short* lp = wlo + l*8;
  float (*Z)[ZP] = zb[w];

  float s0[8] = {0,0,0,0,0,0,0,0};
  float s1[8] = {0,0,0,0,0,0,0,0};

  int ngroups = (rows + 63) >> 6;
  for (int g = blockIdx.x; g < ngroups; g += gridDim.x){
    int rload = g*64 + w*16 + n15;
    bool okload = rload < rows;
    const float* ap = in + (size_t)(okload ? rload : 0)*H + quad*8;

    short8 ah[4], al[4];
    #pragma unroll
    for (int ks = 0; ks < 4; ++ks){
      float4 a0 = okload ? *(const float4*)(ap + ks*32 + 0) : make_float4(0.f,0.f,0.f,0.f);
      float4 a1 = okload ? *(const float4*)(ap + ks*32 + 4) : make_float4(0.f,0.f,0.f,0.f);
      float av[8] = {a0.x,a0.y,a0.z,a0.w,a1.x,a1.y,a1.z,a1.w};
      conv8(av, ah[ks], al[ks]);
    }

    floatx4 acc[8] = {};
    #pragma unroll
    for (int ks = 0; ks < 4; ++ks){
      #pragma unroll
      for (int nt = 0; nt < 8; ++nt){
        short8 bh = *(const short8*)(hp + (ks*8 + nt)*512);
        short8 bl = *(const short8*)(lp + (ks*8 + nt)*512);
        acc[nt] = __builtin_amdgcn_mfma_f32_16x16x32_bf16(ah[ks], bh, acc[nt], 0, 0, 0);
        acc[nt] = __builtin_amdgcn_mfma_f32_16x16x32_bf16(al[ks], bh, acc[nt], 0, 0, 0);
        acc[nt] = __builtin_amdgcn_mfma_f32_16x16x32_bf16(ah[ks], bl, acc[nt], 0, 0, 0);
      }
    }

    int rbase = g*64 + w*16;
    #pragma unroll
    for (int half = 0; half < 2; ++half){
      #pragma unroll
      for (int ntl = 0; ntl < 4; ++ntl){
        int nt = half*4 + ntl;
        float bv = bias[nt*16 + n15];
        #pragma unroll
        for (int reg = 0; reg < 4; ++reg){
          float v = acc[nt][reg] + bv;
          if (rbase + quad*4 + reg < rows){ s0[nt] += v; s1[nt] += v*v; }
          Z[quad*4 + reg][ntl*16 + n15] = v;
        }
      }
      #pragma unroll
      for (int ii = 0; ii < 2; ++ii){
        int row = (l >> 3) + 8*ii;
        int r = rbase + row;
        if (r < rows){
          float* orow = out + (size_t)r*H + half*64;
          #pragma unroll
          for (int jj = 0; jj < 2; ++jj){
            int c4 = ((l & 7) + 8*jj)*4;
            *(float4*)(orow + c4) = *(const float4*)&Z[row][c4];
          }
        }
      }
    }
  }

  // cross-quad shuffle reduce (f32), cross-wave LDS reduce (f64, zb dead), one partial row/block
  __syncthreads();
  double* red = (double*)&zb[0][0][0];   // 8*H doubles = 8 KB of the 17 KB
  #pragma unroll
  for (int nt = 0; nt < 8; ++nt){
    float a = s0[nt], b = s1[nt];
    a += __shfl_xor(a, 16, 64); b += __shfl_xor(b, 16, 64);
    a += __shfl_xor(a, 32, 64); b += __shfl_xor(b, 32, 64);
    if (quad == 0){
      int col = nt*16 + n15;
      red[(size_t)(w*2+0)*H + col] = (double)a;
      red[(size_t)(w*2+1)*H + col] = (double)b;
    }
  }
  __syncthreads();
  if (tid < H){
    int col = tid;
    double a = red[0*H+col] + red[2*H+col] + red[4*H+col] + red[6*H+col];
    double b = red[1*H+col] + red[3*H+col] + red[5*H+col] + red[7*H+col];
    part[(size_t)(blockIdx.x*2+0)*H + col] = a;
    part[(size_t)(blockIdx.x*2+1)*H + col] = b;
  }
}

// ---------------- BatchNorm (two-stage, no atomics; parallel final reduce) ----------------

__global__ void k_bnstats_p(const float* __restrict__ x, int rows, double* __restrict__ part){
  int g = blockIdx.x*256 + threadIdx.x;
  int c = g & (H-1);
  int s = g >> 7;
  int stride = (gridDim.x*256) >> 7;
  double a = 0.0, b = 0.0;
  for (int r = s; r < rows; r += stride){
    float v = x[(size_t)r*H + c];
    a += v; b += (double)v*(double)v;
  }
  part[(size_t)(s*2+0)*H + c] = a;
  part[(size_t)(s*2+1)*H + c] = b;
}

__global__ void k_bnfin_par(const double* __restrict__ part, int nstreams, int rows,
                            float* __restrict__ muinv){
  __shared__ double sh0[256], sh1[256];
  int c = blockIdx.x;
  int tid = threadIdx.x;
  double a = 0.0, b = 0.0;
  for (int s = tid; s < nstreams; s += 256){
    a += part[(size_t)(s*2+0)*H + c];
    b += part[(size_t)(s*2+1)*H + c];
  }
  sh0[tid] = a; sh1[tid] = b;
  __syncthreads();
  for (int ofs = 128; ofs > 0; ofs >>= 1){
    if (tid < ofs){ sh0[tid] += sh0[tid+ofs]; sh1[tid] += sh1[tid+ofs]; }
    __syncthreads();
  }
  if (tid == 0){
    double mu = sh0[0] / (double)rows;
    double var = sh1[0] / (double)rows - mu*mu;
    muinv[c]   = (float)mu;
    muinv[H+c] = (float)(1.0 / sqrt(var + (double)BN_EPS));
  }
}

__global__ void k_bnapply(float* __restrict__ x, const float* __restrict__ muinv,
                          const float* __restrict__ g, const float* __restrict__ b, int rows){
  int idx = blockIdx.x*256 + threadIdx.x;
  if (idx >= rows*H4) return;
  int r = idx >> 5; int c = (idx & 31) << 2;
  float4 v  = *(const float4*)(x + (size_t)r*H + c);
  float4 mu = *(const float4*)(muinv + c);
  float4 iv = *(const float4*)(muinv + H + c);
  float4 gg = *(const float4*)(g + c);
  float4 bb = *(const float4*)(b + c);
  v.x = (v.x-mu.x)*iv.x*gg.x + bb.x;
  v.y = (v.y-mu.y)*iv.y*gg.y + bb.y;
  v.z = (v.z-mu.z)*iv.z*gg.z + bb.z;
  v.w = (v.w-mu.w)*iv.w*gg.w + bb.w;
  *(float4*)(x + (size_t)r*H + c) = v;
}

// ---------------- layer combine (coalesced float4 streaming) ----------------

__global__ void k_combine(float* __restrict__ h, const float* __restrict__ h1raw,
                          const float* __restrict__ r1, const float* __restrict__ r2,
                          const float* __restrict__ hinter, const float* __restrict__ muinv,
                          const float* __restrict__ bg, const float* __restrict__ bb,
                          const int* __restrict__ nids){
  int idx = blockIdx.x*256 + threadIdx.x;
  if (idx >= FF*H4) return;
  int f = idx >> 5; int c = (idx & 31) << 2;
  int nid = nids[f];
  float vf = (nid >= 0) ? 1.f : 0.f;
  int cid = (nid < 0) ? 0 : nid;
  float4 x  = *(const float4*)(h1raw + (size_t)f*H + c);
  float4 mu = *(const float4*)(muinv + c);
  float4 iv = *(const float4*)(muinv + H + c);
  float4 g4 = *(const float4*)(bg + c);
  float4 b4 = *(const float4*)(bb + c);
  float4 h1;
  h1.x = ((x.x-mu.x)*iv.x*g4.x + b4.x) * vf;
  h1.y = ((x.y-mu.y)*iv.y*g4.y + b4.y) * vf;
  h1.z = ((x.z-mu.z)*iv.z*g4.z + b4.z) * vf;
  h1.w = ((x.w-mu.w)*iv.w*g4.w + b4.w) * vf;
  float4 o;
  if (f % KK == 0){
    float4 hi = *(const float4*)(hinter + (size_t)cid*H + c);
    o.x = h1.x + hi.x*vf; o.y = h1.y + hi.y*vf; o.z = h1.z + hi.z*vf; o.w = h1.w + hi.w*vf;
  } else {
    float4 a  = *(const float4*)(r1 + (size_t)f*H + c);
    float4 rr = *(const float4*)(r2 + (size_t)(f/KK)*H + c);
    o.x = h1.x + a.x + rr.x; o.y = h1.y + a.y + rr.y; o.z = h1.z + a.z + rr.z; o.w = h1.w + a.w + rr.w;
  }
  o.x = fmaxf(o.x,0.f)*vf; o.y = fmaxf(o.y,0.f)*vf; o.z = fmaxf(o.z,0.f)*vf; o.w = fmaxf(o.w,0.f)*vf;
  *(float4*)(h + (size_t)f*H + c) = o;
}

// ---------------- readout ----------------

__global__ void k_hsub(float* __restrict__ hsub, const float* __restrict__ h){
  int idx = blockIdx.x*256 + threadIdx.x;
  if (idx >= SS*H4) return;
  int s = idx >> 5; int c = (idx & 31) << 2;
  float4 acc = make_float4(0.f,0.f,0.f,0.f);
  const float* base = h + (size_t)s*KK*H + c;
  #pragma unroll
  for (int k = 0; k < KK; ++k){
    float4 v = *(const float4*)(base + (size_t)k*H);
    acc.x += v.x; acc.y += v.y; acc.z += v.z; acc.w += v.w;
  }
  *(float4*)(hsub + (size_t)s*H + c) = acc;
}

__global__ void k_poolw(float* __restrict__ poolw, const float* __restrict__ lp,
                        const float* __restrict__ alpha){
  int n = blockIdx.x*256 + threadIdx.x;
  if (n >= NN) return;
  float a = alpha[0];
  float s0 = -a*lp[n*MSUB+0], s1 = -a*lp[n*MSUB+1], s2 = -a*lp[n*MSUB+2], s3 = -a*lp[n*MSUB+3];
  float m = fmaxf(fmaxf(s0,s1), fmaxf(s2,s3));
  float e0 = expf(s0-m), e1 = expf(s1-m), e2 = expf(s2-m), e3 = expf(s3-m);
  float sum = e0+e1+e2+e3;
  poolw[n*MSUB+0] = e0/sum; poolw[n*MSUB+1] = e1/sum;
  poolw[n*MSUB+2] = e2/sum; poolw[n*MSUB+3] = e3/sum;
}

__global__ void k_nodeemb(float* __restrict__ nemb, const float* __restrict__ hsub,
                          const float* __restrict__ poolw){
  int idx = blockIdx.x*256 + threadIdx.x;
  if (idx >= NN*H4) return;
  int n = idx >> 5; int c = (idx & 31) << 2;
  float w0 = poolw[n*MSUB+0], w1 = poolw[n*MSUB+1], w2 = poolw[n*MSUB+2], w3 = poolw[n*MSUB+3];
  const float* base = hsub + (size_t)n*MSUB*H + c;
  float4 v0 = *(const float4*)(base + 0*H);
  float4 v1 = *(const float4*)(base + 1*H);
  float4 v2 = *(const float4*)(base + 2*H);
  float4 v3 = *(const float4*)(base + 3*H);
  float4 o;
  o.x = w0*v0.x + w1*v1.x + w2*v2.x + w3*v3.x;
  o.y = w0*v0.y + w1*v1.y + w2*v2.y + w3*v3.y;
  o.z = w0*v0.z + w1*v1.z + w2*v2.z + w3*v3.z;
  o.w = w0*v0.w + w1*v1.w + w2*v2.w + w3*v3.w;
  *(float4*)(nemb + (size_t)n*H + c) = o;
}

__global__ void k_out(float* __restrict__ out, const float* __restrict__ nemb,
                      const float* __restrict__ muinv, const float* __restrict__ g,
                      const float* __restrict__ b){
  int idx = blockIdx.x*256 + threadIdx.x;
  if (idx >= NBATCH*H) return;
  int bi = idx >> 7; int c = idx & (H-1);
  float mu = muinv[c], iv = muinv[H+c], gg = g[c], bb = b[c];
  float acc = 0.f;
  const float* base = nemb + (size_t)bi*(NN/NBATCH)*H + c;
  for (int i = 0; i < NN/NBATCH; ++i)
    acc += (base[(size_t)i*H] - mu)*iv*gg + bb;
  out[idx] = acc;
}

// ---------------- launch ----------------

extern "C" void kernel_launch(void* const* d_in, const int* in_sizes, int n_in,
                              void* d_out, int out_size, void* d_ws, size_t ws_size,
                              hipStream_t stream) {
  const int*   x_tok      = (const int*)  d_in[0];
  const int*   dist       = (const int*)  d_in[1];
  const int*   node_ids   = (const int*)  d_in[2];
  const int*   sub_batch  = (const int*)  d_in[4];
  const int*   rfi        = (const int*)  d_in[5];
  const int*   intra_ei   = (const int*)  d_in[6];
  const int*   edge_index = (const int*)  d_in[7];
  const float* lp         = (const float*)d_in[9];
  const float* ea_flat    = (const float*)d_in[10];
  const float* edge_attr  = (const float*)d_in[11];
  const float* atom_emb   = (const float*)d_in[12];
  const float* dist_emb   = (const float*)d_in[13];
  const float* logp_w     = (const float*)d_in[14];
  const float* logp_b     = (const float*)d_in[15];
  const float* intra_W1   = (const float*)d_in[16];
  const float* intra_b1   = (const float*)d_in[17];
  const float* intra_W2   = (const float*)d_in[18];
  const float* intra_b2   = (const float*)d_in[19];
  const float* intra_bn_g = (const float*)d_in[20];
  const float* intra_bn_b = (const float*)d_in[21];
  const float* self_W     = (const float*)d_in[22];
  const float* self_b     = (const float*)d_in[23];
  const float* root_W     = (const float*)d_in[24];
  const float* root_b     = (const float*)d_in[25];
  const float* inter_W1   = (const float*)d_in[26];
  const float* inter_b1   = (const float*)d_in[27];
  const float* inter_W2   = (const float*)d_in[28];
  const float* inter_b2   = (const float*)d_in[29];
  const float* inter_bn_g = (const float*)d_in[30];
  const float* inter_bn_b = (const float*)d_in[31];
  const float* ro_bn_g    = (const float*)d_in[32];
  const float* ro_bn_b    = (const float*)d_in[33];
  const float* alpha_pool = (const float*)d_in[34];
  const float* alpha_inter= (const float*)d_in[35];

  const int* isrc = intra_ei;
  const int* idst = intra_ei + EINTRA;
  const int* esrc = edge_index;
  const int* edst = edge_index + EINTER;

  float* out = (float*)d_out;

  char* ws = (char*)d_ws;
  size_t off = 0;
  auto nxt = [&](size_t bytes) -> void* {
    void* p = ws + off;
    off += (bytes + 255) & ~(size_t)255;
    return p;
  };
  const int G_MM_F = 768;                       // 3 blocks/CU (50 KB LDS) x 256 CUs
  const int G_MM_S = (SS + 63)/64;              // 157
  const int G_MM_N = (NN + 63)/64;              // 40
  const int G_BN_S = 32;                        // small-BN stat blocks -> 64 streams

  float*  h      = (float*) nxt((size_t)FF*H*4);
  float*  hmid   = (float*) nxt((size_t)FF*H*4);
  float*  tbuf   = (float*) nxt((size_t)FF*H*4);
  float*  r2     = (float*) nxt((size_t)SS*H*4);
  float*  canon  = (float*) nxt((size_t)NN*H*4);
  float*  agg2   = (float*) nxt((size_t)NN*H*4);
  float*  hsub   = (float*) nxt((size_t)SS*H*4);
  float*  nemb   = (float*) nxt((size_t)NN*H*4);
  float*  htw    = (float*) nxt((size_t)SS*4);
  float*  poolw  = (float*) nxt((size_t)NN*MSUB*4);
  double* statsA = (double*)nxt((size_t)G_MM_F*2*H*8);       // per-block partials (1.5 MB)
  double* statsB = (double*)nxt((size_t)(G_BN_S*2)*2*H*8);   // 64-stream partials
  float*  muinvA = (float*) nxt((size_t)2*H*4);
  float*  muinvB = (float*) nxt((size_t)2*H*4);
  short*  whiG   = (short*) nxt((size_t)24*WF_SHORTS*2);     // hi-split frag-major W (768 KB)
  short*  wloG   = (short*) nxt((size_t)24*WF_SHORTS*2);     // lo-split frag-major W (768 KB)
  int*    icnt   = (int*)   nxt((size_t)FF*4);
  int*    ibeid  = (int*)   nxt((size_t)FF*CAP_I*4);
  int*    ecnt   = (int*)   nxt((size_t)NN*4);
  int*    ebeid  = (int*)   nxt((size_t)NN*CAP_E*4);
  int*    irow   = (int*)   nxt((size_t)FF*4);
  int*    erow   = (int*)   nxt((size_t)NN*4);
  int2*   ies    = (int2*)  nxt((size_t)EINTRA*8);
  int2*   ees    = (int2*)  nxt((size_t)EINTER*8);
  int*    gcnt   = (int*)   nxt((size_t)2*4);
  (void)ws_size; (void)n_in; (void)in_sizes; (void)out_size; (void)sub_batch;

  const int G_FH4 = FF*H4/256;
  const int G_SH4 = SS*H4/256;
  const int G_NH4 = (NN*H4 + 255)/256;
  const int G_N   = (NN + 255)/256;
  const int G_F   = (FF + 255)/256;

  // zero counters (ws poisoned before every call)
  k_zeroi<<<G_F, 256, 0, stream>>>(icnt, FF);
  k_zeroi<<<G_N, 256, 0, stream>>>(ecnt, NN);
  k_zeroi<<<1, 256, 0, stream>>>(gcnt, 2);

  // W split prep (once)
  k_wprep<<<24*8, 256, 0, stream>>>(intra_W1, intra_W2, self_W, root_W,
                                    inter_W1, inter_W2, whiG, wloG);

  // CSR buckets -> packed {e,src} segments
  k_bucket<<<(EINTRA+255)/256, 256, 0, stream>>>(idst, EINTRA, icnt, ibeid, CAP_I);
  k_bucket<<<(EINTER+255)/256, 256, 0, stream>>>(edst, EINTER, ecnt, ebeid, CAP_E);
  k_scan<<<G_F, 256, 0, stream>>>(icnt, FF, CAP_I, irow, gcnt);
  k_scan<<<G_N, 256, 0, stream>>>(ecnt, NN, CAP_E, erow, gcnt+1);
  k_csr_fill<<<G_F, 256, 0, stream>>>(icnt, irow, ibeid, isrc, FF, CAP_I, ies);
  k_csr_fill<<<G_N, 256, 0, stream>>>(ecnt, erow, ebeid, esrc, NN, CAP_E, ees);

  // input encoding + HT weights
  k_encode<<<G_FH4, 256, 0, stream>>>(h, x_tok, dist, node_ids, sub_batch, lp,
                                      atom_emb, dist_emb, logp_w, logp_b);
  k_htw<<<G_N, 256, 0, stream>>>(node_ids, rfi, lp, alpha_inter, htw);

  for (int l = 0; l < NLAYER; ++l){
    const short* hi_iW1 = whiG + (size_t)(l*6+0)*WF_SHORTS;
    const short* hi_iW2 = whiG + (size_t)(l*6+1)*WF_SHORTS;
    const short* hi_sW  = whiG + (size_t)(l*6+2)*WF_SHORTS;
    const short* hi_rW  = whiG + (size_t)(l*6+3)*WF_SHORTS;
    const short* hi_nW1 = whiG + (size_t)(l*6+4)*WF_SHORTS;
    const short* hi_nW2 = whiG + (size_t)(l*6+5)*WF_SHORTS;
    const short* lo_iW1 = wloG + (size_t)(l*6+0)*WF_SHORTS;
    const short* lo_iW2 = wloG + (size_t)(l*6+1)*WF_SHORTS;
    const short* lo_sW  = wloG + (size_t)(l*6+2)*WF_SHORTS;
    const short* lo_rW  = wloG + (size_t)(l*6+3)*WF_SHORTS;
    const short* lo_nW1 = wloG + (size_t)(l*6+4)*WF_SHORTS;
    const short* lo_nW2 = wloG + (size_t)(l*6+5)*WF_SHORTS;

    // intra GINE stage1 (CSR gather)
    k_gine_gather2<<<G_FH4, 256, 0, stream>>>(hmid, h, ea_flat, icnt, irow, ies, FF, CAP_I);
    // MLP via split-bf16 MFMA; W2 pass fuses BN-stats partial accumulation
    k_mm_mfma<<<G_MM_F, 256, 0, stream>>>(hmid, tbuf, FF, hi_iW1, lo_iW1,
                                          intra_b1 + (size_t)l*H, 1, nullptr);
    k_mm_mfma_stats<<<G_MM_F, 256, 0, stream>>>(tbuf, hmid, FF, hi_iW2, lo_iW2,
                                                intra_b2 + (size_t)l*H, statsA);
    k_bnfin_par<<<H, 256, 0, stream>>>(statsA, G_MM_F, FF, muinvA);

    // HT root gather to canonical nodes
    k_canon<<<G_NH4, 256, 0, stream>>>(canon, h, htw, rfi);
    // r2[s] = h[rfi[s]] @ root_W + root_b
    k_mm_mfma<<<G_MM_S, 256, 0, stream>>>(h, r2, SS, hi_rW, lo_rW,
                                          root_b + (size_t)l*H, 0, rfi);

    // inter GINE (CSR gather)
    k_gine_gather2<<<G_NH4, 256, 0, stream>>>(agg2, canon, edge_attr, ecnt, erow, ees, NN, CAP_E);
    k_mm_mfma<<<G_MM_N, 256, 0, stream>>>(agg2, tbuf, NN, hi_nW1, lo_nW1,
                                          inter_b1 + (size_t)l*H, 1, nullptr);
    k_mm_mfma<<<G_MM_N, 256, 0, stream>>>(tbuf, agg2, NN, hi_nW2, lo_nW2,
                                          inter_b2 + (size_t)l*H, 0, nullptr);
    k_bnstats_p<<<G_BN_S, 256, 0, stream>>>(agg2, NN, statsB);
    k_bnfin_par<<<H, 256, 0, stream>>>(statsB, G_BN_S*2, NN, muinvB);
    k_bnapply<<<G_NH4, 256, 0, stream>>>(agg2, muinvB, inter_bn_g + (size_t)l*H,
                                         inter_bn_b + (size_t)l*H, NN);

    // r1 = h @ self_W + self_b
    k_mm_mfma<<<G_MM_F, 256, 0, stream>>>(h, tbuf, FF, hi_sW, lo_sW,
                                          self_b + (size_t)l*H, 0, nullptr);
    // combine -> new h (coalesced float4 streaming)
    k_combine<<<G_FH4, 256, 0, stream>>>(h, hmid, tbuf, r2, agg2, muinvA,
                                         intra_bn_g + (size_t)l*H,
                                         intra_bn_b + (size_t)l*H, node_ids);
  }

  // readout
  k_hsub<<<G_SH4, 256, 0, stream>>>(hsub, h);
  k_poolw<<<G_N, 256, 0, stream>>>(poolw, lp, alpha_pool);
  k_nodeemb<<<G_NH4, 256, 0, stream>>>(nemb, hsub, poolw);
  k_bnstats_p<<<G_BN_S, 256, 0, stream>>>(nemb, NN, statsB);
  k_bnfin_par<<<H, 256, 0, stream>>>(statsB, G_BN_S*2, NN, muinvB);
  k_out<<<(NBATCH*H+255)/256, 256, 0, stream>>>(out, nemb, muinvB, ro_bn_g, ro_bn_b);
}

// Round 11
// 1836.244 us; speedup vs baseline: 1.6013x; 1.1251x over previous
//
#include <hip/hip_runtime.h>
#include <math.h>

#define H 128
#define H4 (H/4)
#define KK 12
#define MSUB 4
#define FF 120000
#define SS 10000
#define NN 2500
#define NBATCH 50
#define NLAYER 4
#define EINTRA 240000
#define EINTER 40000
#define HH (H*H)
#define BN_EPS 1e-5f
#define CAP_I 32
#define CAP_E 96
#define WF_SHORTS 16384   // per matrix per split: 128*128

typedef short short8 __attribute__((ext_vector_type(8)));
typedef float floatx4 __attribute__((ext_vector_type(4)));

__device__ __forceinline__ unsigned short f2bf_rne(float x){
  unsigned u = __float_as_uint(x);
  unsigned r = u + 0x7FFFu + ((u >> 16) & 1u);
  return (unsigned short)(r >> 16);
}

// ---------------- small helpers ----------------

__global__ void k_zeroi(int* __restrict__ p, int n){
  int i = blockIdx.x*256 + threadIdx.x;
  if (i < n) p[i] = 0;
}

// ---------------- CSR bucket build ----------------

__global__ void k_bucket(const int* __restrict__ dst, int E, int* __restrict__ cnt,
                         int* __restrict__ beid, int cap){
  int e = blockIdx.x*256 + threadIdx.x;
  if (e >= E) return;
  int d = dst[e];
  int p = atomicAdd(&cnt[d], 1);
  if (p < cap) beid[(size_t)d*cap + p] = e;
}

__global__ void k_scan(const int* __restrict__ cnt, int rows, int cap,
                       int* __restrict__ rowptr, int* __restrict__ gcount){
  __shared__ int sdata[256];
  __shared__ int sbase;
  int tid = threadIdx.x;
  int r = blockIdx.x*256 + tid;
  int v = 0;
  if (r < rows){ v = cnt[r]; if (v > cap) v = cap; }
  sdata[tid] = v;
  __syncthreads();
  for (int ofs = 1; ofs < 256; ofs <<= 1){
    int t = (tid >= ofs) ? sdata[tid-ofs] : 0;
    __syncthreads();
    sdata[tid] += t;
    __syncthreads();
  }
  if (tid == 255) sbase = atomicAdd(gcount, sdata[255]);
  __syncthreads();
  if (r < rows) rowptr[r] = sbase + sdata[tid] - v;
}

__global__ void k_csr_fill(const int* __restrict__ cnt, const int* __restrict__ rowptr,
                           const int* __restrict__ beid, const int* __restrict__ src,
                           int rows, int cap, int2* __restrict__ es){
  int f = blockIdx.x*256 + threadIdx.x;
  if (f >= rows) return;
  int n = cnt[f]; if (n > cap) n = cap;
  int base = rowptr[f];
  const int* bl = beid + (size_t)f*cap;
  for (int i = 0; i < n; ++i){
    int e = bl[i];
    es[base + i] = make_int2(e, src[e]);
  }
}

// ---------------- W split prep (frag-major hi+lo), once ----------------
// idx per matrix: (ks*8+nt)*512 + lane*8 + j; 24 mats: layer*6 + {0=iW1,1=iW2,2=selfW,3=rootW,4=inW1,5=inW2}

__global__ void k_wprep(const float* __restrict__ iW1, const float* __restrict__ iW2,
                        const float* __restrict__ sW,  const float* __restrict__ rW,
                        const float* __restrict__ nW1, const float* __restrict__ nW2,
                        short* __restrict__ whiG, short* __restrict__ wloG){
  int mat = blockIdx.x >> 3;                      // 24 matrices, 8 blocks each
  int t = (blockIdx.x & 7)*256 + threadIdx.x;     // 0..2047 : (ks,nt,lane)
  int l = t & 63, nt = (t >> 6) & 7, ks = t >> 9;
  int layer = mat / 6, which = mat % 6;
  const float* W;
  switch (which){
    case 0: W = iW1; break; case 1: W = iW2; break; case 2: W = sW; break;
    case 3: W = rW;  break; case 4: W = nW1; break; default: W = nW2; break;
  }
  W += (size_t)layer*HH;
  short* oh = whiG + (size_t)mat*WF_SHORTS;
  short* ol = wloG + (size_t)mat*WF_SHORTS;
  int quad = l >> 4, n15 = l & 15;
  #pragma unroll
  for (int j = 0; j < 8; ++j){
    int k = ks*32 + quad*8 + j;
    int n = nt*16 + n15;
    float v = W[(size_t)k*H + n];
    unsigned short hb = f2bf_rne(v);
    float hf = __uint_as_float((unsigned)hb << 16);
    int idx = (ks*8 + nt)*512 + l*8 + j;
    oh[idx] = (short)hb;
    ol[idx] = (short)f2bf_rne(v - hf);
  }
}

// ---------------- input encoding ----------------

__global__ void k_encode(float* __restrict__ h, const int* __restrict__ xtok,
                         const int* __restrict__ dist, const int* __restrict__ nids,
                         const int* __restrict__ subb, const float* __restrict__ lp,
                         const float* __restrict__ aemb, const float* __restrict__ demb,
                         const float* __restrict__ lw, const float* __restrict__ lb){
  int idx = blockIdx.x*256 + threadIdx.x;
  if (idx >= FF*H4) return;
  int f = idx >> 5; int c = (idx & 31) << 2;
  float vf = (nids[f] >= 0) ? 1.f : 0.f;
  float l = lp[subb[f]];
  float4 a = *(const float4*)(aemb + (size_t)xtok[f]*H + c);
  float4 d = *(const float4*)(demb + (size_t)dist[f]*H + c);
  float4 w = *(const float4*)(lw + c);
  float4 b = *(const float4*)(lb + c);
  float4 o;
  o.x = (a.x + d.x + fmaxf(fmaf(l, w.x, b.x), 0.f)) * vf;
  o.y = (a.y + d.y + fmaxf(fmaf(l, w.y, b.y), 0.f)) * vf;
  o.z = (a.z + d.z + fmaxf(fmaf(l, w.z, b.z), 0.f)) * vf;
  o.w = (a.w + d.w + fmaxf(fmaf(l, w.w, b.w), 0.f)) * vf;
  *(float4*)(h + (size_t)f*H + c) = o;
}

// ---------------- HT weights ----------------

__global__ void k_htw(const int* __restrict__ nids, const int* __restrict__ rfi,
                      const float* __restrict__ lp, const float* __restrict__ alpha,
                      float* __restrict__ htw){
  int n = blockIdx.x*256 + threadIdx.x;
  if (n >= NN) return;
  float a = alpha[0];
  float w[MSUB]; float sum = 0.f;
  #pragma unroll
  for (int m = 0; m < MSUB; ++m){
    int s = n*MSUB + m;
    int rid = nids[rfi[s]];
    float wm = (rid >= 0) ? expf(-a*lp[s]) : 0.f;
    w[m] = wm; sum += wm;
  }
  float inv = 1.f / (sum + 1e-16f);
  #pragma unroll
  for (int m = 0; m < MSUB; ++m) htw[n*MSUB + m] = w[m]*inv;
}

// ---------------- GINE gather (CSR form) ----------------

__global__ void k_gine_gather2(float* __restrict__ outa, const float* __restrict__ x,
                               const float* __restrict__ ea, const int* __restrict__ cnt,
                               const int* __restrict__ rowptr, const int2* __restrict__ es,
                               int rows, int cap){
  int idx = blockIdx.x*256 + threadIdx.x;
  if (idx >= rows*H4) return;
  int f = idx >> 5; int c = (idx & 31) << 2;
  float4 acc = *(const float4*)(x + (size_t)f*H + c);
  int n = cnt[f]; if (n > cap) n = cap;
  const int2* p = es + rowptr[f];
  int i = 0;
  for (; i + 2 <= n; i += 2){
    int2 e0 = p[i];
    int2 e1 = p[i+1];
    float4 x0 = *(const float4*)(x + (size_t)e0.y*H + c);
    float4 a0 = *(const float4*)(ea + (size_t)e0.x*H + c);
    float4 x1 = *(const float4*)(x + (size_t)e1.y*H + c);
    float4 a1 = *(const float4*)(ea + (size_t)e1.x*H + c);
    acc.x += fmaxf(x0.x + a0.x, 0.f) + fmaxf(x1.x + a1.x, 0.f);
    acc.y += fmaxf(x0.y + a0.y, 0.f) + fmaxf(x1.y + a1.y, 0.f);
    acc.z += fmaxf(x0.z + a0.z, 0.f) + fmaxf(x1.z + a1.z, 0.f);
    acc.w += fmaxf(x0.w + a0.w, 0.f) + fmaxf(x1.w + a1.w, 0.f);
  }
  if (i < n){
    int2 e0 = p[i];
    float4 x0 = *(const float4*)(x + (size_t)e0.y*H + c);
    float4 a0 = *(const float4*)(ea + (size_t)e0.x*H + c);
    acc.x += fmaxf(x0.x + a0.x, 0.f);
    acc.y += fmaxf(x0.y + a0.y, 0.f);
    acc.z += fmaxf(x0.z + a0.z, 0.f);
    acc.w += fmaxf(x0.w + a0.w, 0.f);
  }
  *(float4*)(outa + (size_t)f*H + c) = acc;
}

// ---------------- HT root gather ----------------

__global__ void k_canon(float* __restrict__ canon, const float* __restrict__ h,
                        const float* __restrict__ htw, const int* __restrict__ rfi){
  int idx = blockIdx.x*256 + threadIdx.x;
  if (idx >= NN*H4) return;
  int n = idx >> 5; int c = (idx & 31) << 2;
  float4 acc = make_float4(0.f,0.f,0.f,0.f);
  #pragma unroll
  for (int m = 0; m < MSUB; ++m){
    int s = n*MSUB + m;
    float w = htw[s];
    const float* p = h + (size_t)rfi[s]*H + c;
    acc.x += w*p[0]; acc.y += w*p[1]; acc.z += w*p[2]; acc.w += w*p[3];
  }
  *(float4*)(canon + (size_t)n*H + c) = acc;
}

// ---------------- MFMA helpers ----------------

__device__ __forceinline__ void load_a_raw(const float* __restrict__ in, int rows, int rload,
                                           const int* __restrict__ gather, int quad, float4* ra){
  bool ok = rload < rows;
  int ir = ok ? (gather ? gather[rload] : rload) : 0;
  const float* ap = in + (size_t)ir*H + quad*8;
  #pragma unroll
  for (int ks = 0; ks < 4; ++ks){
    ra[ks*2+0] = ok ? *(const float4*)(ap + ks*32 + 0) : make_float4(0.f,0.f,0.f,0.f);
    ra[ks*2+1] = ok ? *(const float4*)(ap + ks*32 + 4) : make_float4(0.f,0.f,0.f,0.f);
  }
}

__device__ __forceinline__ void conv_a(const float4* ra, short8* ah, short8* al){
  #pragma unroll
  for (int ks = 0; ks < 4; ++ks){
    float av[8] = {ra[ks*2].x, ra[ks*2].y, ra[ks*2].z, ra[ks*2].w,
                   ra[ks*2+1].x, ra[ks*2+1].y, ra[ks*2+1].z, ra[ks*2+1].w};
    #pragma unroll
    for (int j = 0; j < 8; ++j){
      unsigned short hb = f2bf_rne(av[j]);
      float hf = __uint_as_float((unsigned)hb << 16);
      ah[ks][j] = (short)hb;
      al[ks][j] = (short)f2bf_rne(av[j] - hf);
    }
  }
}

// ---------------- split-bf16 MFMA matmul (prefetch pipeline, both splits LDS-copied) ----------------
// Prologue: straight 16B copies whiG/wloG -> 64 KB LDS (no convert, W L2-resident across blocks).
// Per split: 2048 short8 units / 256 threads = 8 iterations.
// A-load for NEXT group issued before current group's convert+MFMA. Scalar C-layout stores.

__global__ __launch_bounds__(256, 2) void k_mm_mfma(
    const float* __restrict__ in, float* __restrict__ out, int rows,
    const short* __restrict__ whiG, const short* __restrict__ wloG,
    const float* __restrict__ bias, int do_relu, const int* __restrict__ gather)
{
  __shared__ __align__(16) short wfrag[2*WF_SHORTS];   // [split][ks][nt][lane][j], 64 KB
  int tid = threadIdx.x;
  int w = tid >> 6, l = tid & 63;
  int quad = l >> 4, n15 = l & 15;

  {
    short8* wdst = (short8*)wfrag;
    const short8* hs = (const short8*)whiG;
    const short8* ls = (const short8*)wloG;
    #pragma unroll
    for (int i = 0; i < 8; ++i) wdst[tid + i*256] = hs[tid + i*256];
    #pragma unroll
    for (int i = 0; i < 8; ++i) wdst[2048 + tid + i*256] = ls[tid + i*256];
  }
  __syncthreads();

  const short* hp = wfrag + l*8;
  const short* lp = wfrag + WF_SHORTS + l*8;

  int ngroups = (rows + 63) >> 6;
  int g = blockIdx.x;
  float4 ra[8];
  if (g < ngroups) load_a_raw(in, rows, g*64 + w*16 + n15, gather, quad, ra);
  while (g < ngroups){
    int gn = g + gridDim.x;
    short8 ah[4], al[4];
    conv_a(ra, ah, al);
    if (gn < ngroups) load_a_raw(in, rows, gn*64 + w*16 + n15, gather, quad, ra);

    floatx4 acc[8] = {};
    #pragma unroll
    for (int ks = 0; ks < 4; ++ks){
      #pragma unroll
      for (int nt = 0; nt < 8; ++nt){
        short8 bh = *(const short8*)(hp + (ks*8 + nt)*512);
        short8 bl = *(const short8*)(lp + (ks*8 + nt)*512);
        acc[nt] = __builtin_amdgcn_mfma_f32_16x16x32_bf16(ah[ks], bh, acc[nt], 0, 0, 0);
        acc[nt] = __builtin_amdgcn_mfma_f32_16x16x32_bf16(al[ks], bh, acc[nt], 0, 0, 0);
        acc[nt] = __builtin_amdgcn_mfma_f32_16x16x32_bf16(ah[ks], bl, acc[nt], 0, 0, 0);
      }
    }

    int rbase = g*64 + w*16 + quad*4;
    #pragma unroll
    for (int nt = 0; nt < 8; ++nt){
      int col = nt*16 + n15;
      float bv = bias[col];
      #pragma unroll
      for (int reg = 0; reg < 4; ++reg){
        int r = rbase + reg;
        if (r < rows){
          float v = acc[nt][reg] + bv;
          if (do_relu) v = fmaxf(v, 0.f);
          out[(size_t)r*H + col] = v;
        }
      }
    }
    g = gn;
  }
}

// ---------------- same matmul + fused BN-stats (no prefetch: register budget; f32 lane sums) ----------------

__global__ __launch_bounds__(256, 2) void k_mm_mfma_stats(
    const float* __restrict__ in, float* __restrict__ out, int rows,
    const short* __restrict__ whiG, const short* __restrict__ wloG,
    const float* __restrict__ bias, double* __restrict__ part)
{
  __shared__ __align__(16) short wfrag[2*WF_SHORTS];   // 64 KB (reused as f64 red after loop)
  int tid = threadIdx.x;
  int w = tid >> 6, l = tid & 63;
  int quad = l >> 4, n15 = l & 15;

  {
    short8* wdst = (short8*)wfrag;
    const short8* hs = (const short8*)whiG;
    const short8* ls = (const short8*)wloG;
    #pragma unroll
    for (int i = 0; i < 8; ++i) wdst[tid + i*256] = hs[tid + i*256];
    #pragma unroll
    for (int i = 0; i < 8; ++i) wdst[2048 + tid + i*256] = ls[tid + i*256];
  }
  __syncthreads();

  const short* hp = wfrag + l*8;
  const short* lp = wfrag + WF_SHORTS + l*8;

  float s0[8] = {0,0,0,0,0,0,0,0};
  float s1[8] = {0,0,0,0,0,0,0,0};

  int ngroups = (rows + 63) >> 6;
  for (int g = blockIdx.x; g < ngroups; g += gridDim.x){
    int rload = g*64 + w*16 + n15;
    bool okload = rload < rows;
    const float* ap = in + (size_t)(okload ? rload : 0)*H + quad*8;

    short8 ah[4], al[4];
    #pragma unroll
    for (int ks = 0; ks < 4; ++ks){
      float4 a0 = okload ? *(const float4*)(ap + ks*32 + 0) : make_float4(0.f,0.f,0.f,0.f);
      float4 a1 = okload ? *(const float4*)(ap + ks*32 + 4) : make_float4(0.f,0.f,0.f,0.f);
      float av[8] = {a0.x,a0.y,a0.z,a0.w,a1.x,a1.y,a1.z,a1.w};
      #pragma unroll
      for (int j = 0; j < 8; ++j){
        unsigned short hb = f2bf_rne(av[j]);
        float hf = __uint_as_float((unsigned)hb << 16);
        ah[ks][j] = (short)hb;
        al[ks][j] = (short)f2bf_rne(av[j] - hf);
      }
    }

    floatx4 acc[8] = {};
    #pragma unroll
    for (int ks = 0; ks < 4; ++ks){
      #pragma unroll
      for (int nt = 0; nt < 8; ++nt){
        short8 bh = *(const short8*)(hp + (ks*8 + nt)*512);
        short8 bl = *(const short8*)(lp + (ks*8 + nt)*512);
        acc[nt] = __builtin_amdgcn_mfma_f32_16x16x32_bf16(ah[ks], bh, acc[nt], 0, 0, 0);
        acc[nt] = __builtin_amdgcn_mfma_f32_16x16x32_bf16(al[ks], bh, acc[nt], 0, 0, 0);
        acc[nt] = __builtin_amdgcn_mfma_f32_16x16x32_bf16(ah[ks], bl, acc[nt], 0, 0, 0);
      }
    }

    int rbase = g*64 + w*16 + quad*4;
    #pragma unroll
    for (int nt = 0; nt < 8; ++nt){
      int col = nt*16 + n15;
      float bv = bias[col];
      #pragma unroll
      for (int reg = 0; reg < 4; ++reg){
        int r = rbase + reg;
        if (r < rows){
          float v = acc[nt][reg] + bv;
          out[(size_t)r*H + col] = v;
          s0[nt] += v;
          s1[nt] += v*v;
        }
      }
    }
  }

  // cross-quad shuffle reduce (f32), cross-wave LDS reduce (f64, wfrag dead), one partial row/block
  __syncthreads();
  double* red = (double*)&wfrag[0];   // 8*H doubles = 8 KB of the 64 KB
  #pragma unroll
  for (int nt = 0; nt < 8; ++nt){
    float a = s0[nt], b = s1[nt];
    a += __shfl_xor(a, 16, 64); b += __shfl_xor(b, 16, 64);
    a += __shfl_xor(a, 32, 64); b += __shfl_xor(b, 32, 64);
    if (quad == 0){
      int col = nt*16 + n15;
      red[(size_t)(w*2+0)*H + col] = (double)a;
      red[(size_t)(w*2+1)*H + col] = (double)b;
    }
  }
  __syncthreads();
  if (tid < H){
    int col = tid;
    double a = red[0*H+col] + red[2*H+col] + red[4*H+col] + red[6*H+col];
    double b = red[1*H+col] + red[3*H+col] + red[5*H+col] + red[7*H+col];
    part[(size_t)(blockIdx.x*2+0)*H + col] = a;
    part[(size_t)(blockIdx.x*2+1)*H + col] = b;
  }
}

// ---------------- BatchNorm (two-stage, no atomics; parallel final reduce) ----------------

__global__ void k_bnstats_p(const float* __restrict__ x, int rows, double* __restrict__ part){
  int g = blockIdx.x*256 + threadIdx.x;
  int c = g & (H-1);
  int s = g >> 7;
  int stride = (gridDim.x*256) >> 7;
  double a = 0.0, b = 0.0;
  for (int r = s; r < rows; r += stride){
    float v = x[(size_t)r*H + c];
    a += v; b += (double)v*(double)v;
  }
  part[(size_t)(s*2+0)*H + c] = a;
  part[(size_t)(s*2+1)*H + c] = b;
}

__global__ void k_bnfin_par(const double* __restrict__ part, int nstreams, int rows,
                            float* __restrict__ muinv){
  __shared__ double sh0[256], sh1[256];
  int c = blockIdx.x;
  int tid = threadIdx.x;
  double a = 0.0, b = 0.0;
  for (int s = tid; s < nstreams; s += 256){
    a += part[(size_t)(s*2+0)*H + c];
    b += part[(size_t)(s*2+1)*H + c];
  }
  sh0[tid] = a; sh1[tid] = b;
  __syncthreads();
  for (int ofs = 128; ofs > 0; ofs >>= 1){
    if (tid < ofs){ sh0[tid] += sh0[tid+ofs]; sh1[tid] += sh1[tid+ofs]; }
    __syncthreads();
  }
  if (tid == 0){
    double mu = sh0[0] / (double)rows;
    double var = sh1[0] / (double)rows - mu*mu;
    muinv[c]   = (float)mu;
    muinv[H+c] = (float)(1.0 / sqrt(var + (double)BN_EPS));
  }
}

__global__ void k_bnapply(float* __restrict__ x, const float* __restrict__ muinv,
                          const float* __restrict__ g, const float* __restrict__ b, int rows){
  int idx = blockIdx.x*256 + threadIdx.x;
  if (idx >= rows*H4) return;
  int r = idx >> 5; int c = (idx & 31) << 2;
  float4 v  = *(const float4*)(x + (size_t)r*H + c);
  float4 mu = *(const float4*)(muinv + c);
  float4 iv = *(const float4*)(muinv + H + c);
  float4 gg = *(const float4*)(g + c);
  float4 bb = *(const float4*)(b + c);
  v.x = (v.x-mu.x)*iv.x*gg.x + bb.x;
  v.y = (v.y-mu.y)*iv.y*gg.y + bb.y;
  v.z = (v.z-mu.z)*iv.z*gg.z + bb.z;
  v.w = (v.w-mu.w)*iv.w*gg.w + bb.w;
  *(float4*)(x + (size_t)r*H + c) = v;
}

// ---------------- layer combine (coalesced float4 streaming) ----------------

__global__ void k_combine(float* __restrict__ h, const float* __restrict__ h1raw,
                          const float* __restrict__ r1, const float* __restrict__ r2,
                          const float* __restrict__ hinter, const float* __restrict__ muinv,
                          const float* __restrict__ bg, const float* __restrict__ bb,
                          const int* __restrict__ nids){
  int idx = blockIdx.x*256 + threadIdx.x;
  if (idx >= FF*H4) return;
  int f = idx >> 5; int c = (idx & 31) << 2;
  int nid = nids[f];
  float vf = (nid >= 0) ? 1.f : 0.f;
  int cid = (nid < 0) ? 0 : nid;
  float4 x  = *(const float4*)(h1raw + (size_t)f*H + c);
  float4 mu = *(const float4*)(muinv + c);
  float4 iv = *(const float4*)(muinv + H + c);
  float4 g4 = *(const float4*)(bg + c);
  float4 b4 = *(const float4*)(bb + c);
  float4 h1;
  h1.x = ((x.x-mu.x)*iv.x*g4.x + b4.x) * vf;
  h1.y = ((x.y-mu.y)*iv.y*g4.y + b4.y) * vf;
  h1.z = ((x.z-mu.z)*iv.z*g4.z + b4.z) * vf;
  h1.w = ((x.w-mu.w)*iv.w*g4.w + b4.w) * vf;
  float4 o;
  if (f % KK == 0){
    float4 hi = *(const float4*)(hinter + (size_t)cid*H + c);
    o.x = h1.x + hi.x*vf; o.y = h1.y + hi.y*vf; o.z = h1.z + hi.z*vf; o.w = h1.w + hi.w*vf;
  } else {
    float4 a  = *(const float4*)(r1 + (size_t)f*H + c);
    float4 rr = *(const float4*)(r2 + (size_t)(f/KK)*H + c);
    o.x = h1.x + a.x + rr.x; o.y = h1.y + a.y + rr.y; o.z = h1.z + a.z + rr.z; o.w = h1.w + a.w + rr.w;
  }
  o.x = fmaxf(o.x,0.f)*vf; o.y = fmaxf(o.y,0.f)*vf; o.z = fmaxf(o.z,0.f)*vf; o.w = fmaxf(o.w,0.f)*vf;
  *(float4*)(h + (size_t)f*H + c) = o;
}

// ---------------- readout ----------------

__global__ void k_hsub(float* __restrict__ hsub, const float* __restrict__ h){
  int idx = blockIdx.x*256 + threadIdx.x;
  if (idx >= SS*H4) return;
  int s = idx >> 5; int c = (idx & 31) << 2;
  float4 acc = make_float4(0.f,0.f,0.f,0.f);
  const float* base = h + (size_t)s*KK*H + c;
  #pragma unroll
  for (int k = 0; k < KK; ++k){
    float4 v = *(const float4*)(base + (size_t)k*H);
    acc.x += v.x; acc.y += v.y; acc.z += v.z; acc.w += v.w;
  }
  *(float4*)(hsub + (size_t)s*H + c) = acc;
}

__global__ void k_poolw(float* __restrict__ poolw, const float* __restrict__ lp,
                        const float* __restrict__ alpha){
  int n = blockIdx.x*256 + threadIdx.x;
  if (n >= NN) return;
  float a = alpha[0];
  float s0 = -a*lp[n*MSUB+0], s1 = -a*lp[n*MSUB+1], s2 = -a*lp[n*MSUB+2], s3 = -a*lp[n*MSUB+3];
  float m = fmaxf(fmaxf(s0,s1), fmaxf(s2,s3));
  float e0 = expf(s0-m), e1 = expf(s1-m), e2 = expf(s2-m), e3 = expf(s3-m);
  float sum = e0+e1+e2+e3;
  poolw[n*MSUB+0] = e0/sum; poolw[n*MSUB+1] = e1/sum;
  poolw[n*MSUB+2] = e2/sum; poolw[n*MSUB+3] = e3/sum;
}

__global__ void k_nodeemb(float* __restrict__ nemb, const float* __restrict__ hsub,
                          const float* __restrict__ poolw){
  int idx = blockIdx.x*256 + threadIdx.x;
  if (idx >= NN*H4) return;
  int n = idx >> 5; int c = (idx & 31) << 2;
  float w0 = poolw[n*MSUB+0], w1 = poolw[n*MSUB+1], w2 = poolw[n*MSUB+2], w3 = poolw[n*MSUB+3];
  const float* base = hsub + (size_t)n*MSUB*H + c;
  float4 v0 = *(const float4*)(base + 0*H);
  float4 v1 = *(const float4*)(base + 1*H);
  float4 v2 = *(const float4*)(base + 2*H);
  float4 v3 = *(const float4*)(base + 3*H);
  float4 o;
  o.x = w0*v0.x + w1*v1.x + w2*v2.x + w3*v3.x;
  o.y = w0*v0.y + w1*v1.y + w2*v2.y + w3*v3.y;
  o.z = w0*v0.z + w1*v1.z + w2*v2.z + w3*v3.z;
  o.w = w0*v0.w + w1*v1.w + w2*v2.w + w3*v3.w;
  *(float4*)(nemb + (size_t)n*H + c) = o;
}

__global__ void k_out(float* __restrict__ out, const float* __restrict__ nemb,
                      const float* __restrict__ muinv, const float* __restrict__ g,
                      const float* __restrict__ b){
  int idx = blockIdx.x*256 + threadIdx.x;
  if (idx >= NBATCH*H) return;
  int bi = idx >> 7; int c = idx & (H-1);
  float mu = muinv[c], iv = muinv[H+c], gg = g[c], bb = b[c];
  float acc = 0.f;
  const float* base = nemb + (size_t)bi*(NN/NBATCH)*H + c;
  for (int i = 0; i < NN/NBATCH; ++i)
    acc += (base[(size_t)i*H] - mu)*iv*gg + bb;
  out[idx] = acc;
}

// ---------------- launch ----------------

extern "C" void kernel_launch(void* const* d_in, const int* in_sizes, int n_in,
                              void* d_out, int out_size, void* d_ws, size_t ws_size,
                              hipStream_t stream) {
  const int*   x_tok      = (const int*)  d_in[0];
  const int*   dist       = (const int*)  d_in[1];
  const int*   node_ids   = (const int*)  d_in[2];
  const int*   sub_batch  = (const int*)  d_in[4];
  const int*   rfi        = (const int*)  d_in[5];
  const int*   intra_ei   = (const int*)  d_in[6];
  const int*   edge_index = (const int*)  d_in[7];
  const float* lp         = (const float*)d_in[9];
  const float* ea_flat    = (const float*)d_in[10];
  const float* edge_attr  = (const float*)d_in[11];
  const float* atom_emb   = (const float*)d_in[12];
  const float* dist_emb   = (const float*)d_in[13];
  const float* logp_w     = (const float*)d_in[14];
  const float* logp_b     = (const float*)d_in[15];
  const float* intra_W1   = (const float*)d_in[16];
  const float* intra_b1   = (const float*)d_in[17];
  const float* intra_W2   = (const float*)d_in[18];
  const float* intra_b2   = (const float*)d_in[19];
  const float* intra_bn_g = (const float*)d_in[20];
  const float* intra_bn_b = (const float*)d_in[21];
  const float* self_W     = (const float*)d_in[22];
  const float* self_b     = (const float*)d_in[23];
  const float* root_W     = (const float*)d_in[24];
  const float* root_b     = (const float*)d_in[25];
  const float* inter_W1   = (const float*)d_in[26];
  const float* inter_b1   = (const float*)d_in[27];
  const float* inter_W2   = (const float*)d_in[28];
  const float* inter_b2   = (const float*)d_in[29];
  const float* inter_bn_g = (const float*)d_in[30];
  const float* inter_bn_b = (const float*)d_in[31];
  const float* ro_bn_g    = (const float*)d_in[32];
  const float* ro_bn_b    = (const float*)d_in[33];
  const float* alpha_pool = (const float*)d_in[34];
  const float* alpha_inter= (const float*)d_in[35];

  const int* isrc = intra_ei;
  const int* idst = intra_ei + EINTRA;
  const int* esrc = edge_index;
  const int* edst = edge_index + EINTER;

  float* out = (float*)d_out;

  char* ws = (char*)d_ws;
  size_t off = 0;
  auto nxt = [&](size_t bytes) -> void* {
    void* p = ws + off;
    off += (bytes + 255) & ~(size_t)255;
    return p;
  };
  const int G_MM_F = 512;                       // 2 blocks/CU (64 KB LDS) x 256 CUs
  const int G_MM_S = (SS + 63)/64;              // 157
  const int G_MM_N = (NN + 63)/64;              // 40
  const int G_BN_S = 32;                        // small-BN stat blocks -> 64 streams

  float*  h      = (float*) nxt((size_t)FF*H*4);
  float*  hmid   = (float*) nxt((size_t)FF*H*4);
  float*  tbuf   = (float*) nxt((size_t)FF*H*4);
  float*  r2     = (float*) nxt((size_t)SS*H*4);
  float*  canon  = (float*) nxt((size_t)NN*H*4);
  float*  agg2   = (float*) nxt((size_t)NN*H*4);
  float*  hsub   = (float*) nxt((size_t)SS*H*4);
  float*  nemb   = (float*) nxt((size_t)NN*H*4);
  float*  htw    = (float*) nxt((size_t)SS*4);
  float*  poolw  = (float*) nxt((size_t)NN*MSUB*4);
  double* statsA = (double*)nxt((size_t)G_MM_F*2*H*8);       // per-block partials (1 MB)
  double* statsB = (double*)nxt((size_t)(G_BN_S*2)*2*H*8);   // 64-stream partials
  float*  muinvA = (float*) nxt((size_t)2*H*4);
  float*  muinvB = (float*) nxt((size_t)2*H*4);
  short*  whiG   = (short*) nxt((size_t)24*WF_SHORTS*2);     // hi-split frag-major W (768 KB)
  short*  wloG   = (short*) nxt((size_t)24*WF_SHORTS*2);     // lo-split frag-major W (768 KB)
  int*    icnt   = (int*)   nxt((size_t)FF*4);
  int*    ibeid  = (int*)   nxt((size_t)FF*CAP_I*4);
  int*    ecnt   = (int*)   nxt((size_t)NN*4);
  int*    ebeid  = (int*)   nxt((size_t)NN*CAP_E*4);
  int*    irow   = (int*)   nxt((size_t)FF*4);
  int*    erow   = (int*)   nxt((size_t)NN*4);
  int2*   ies    = (int2*)  nxt((size_t)EINTRA*8);
  int2*   ees    = (int2*)  nxt((size_t)EINTER*8);
  int*    gcnt   = (int*)   nxt((size_t)2*4);
  (void)ws_size; (void)n_in; (void)in_sizes; (void)out_size; (void)sub_batch;

  const int G_FH4 = FF*H4/256;
  const int G_SH4 = SS*H4/256;
  const int G_NH4 = (NN*H4 + 255)/256;
  const int G_N   = (NN + 255)/256;
  const int G_F   = (FF + 255)/256;

  // zero counters (ws poisoned before every call)
  k_zeroi<<<G_F, 256, 0, stream>>>(icnt, FF);
  k_zeroi<<<G_N, 256, 0, stream>>>(ecnt, NN);
  k_zeroi<<<1, 256, 0, stream>>>(gcnt, 2);

  // W split prep (once)
  k_wprep<<<24*8, 256, 0, stream>>>(intra_W1, intra_W2, self_W, root_W,
                                    inter_W1, inter_W2, whiG, wloG);

  // CSR buckets -> packed {e,src} segments
  k_bucket<<<(EINTRA+255)/256, 256, 0, stream>>>(idst, EINTRA, icnt, ibeid, CAP_I);
  k_bucket<<<(EINTER+255)/256, 256, 0, stream>>>(edst, EINTER, ecnt, ebeid, CAP_E);
  k_scan<<<G_F, 256, 0, stream>>>(icnt, FF, CAP_I, irow, gcnt);
  k_scan<<<G_N, 256, 0, stream>>>(ecnt, NN, CAP_E, erow, gcnt+1);
  k_csr_fill<<<G_F, 256, 0, stream>>>(icnt, irow, ibeid, isrc, FF, CAP_I, ies);
  k_csr_fill<<<G_N, 256, 0, stream>>>(ecnt, erow, ebeid, esrc, NN, CAP_E, ees);

  // input encoding + HT weights
  k_encode<<<G_FH4, 256, 0, stream>>>(h, x_tok, dist, node_ids, sub_batch, lp,
                                      atom_emb, dist_emb, logp_w, logp_b);
  k_htw<<<G_N, 256, 0, stream>>>(node_ids, rfi, lp, alpha_inter, htw);

  for (int l = 0; l < NLAYER; ++l){
    const short* hi_iW1 = whiG + (size_t)(l*6+0)*WF_SHORTS;
    const short* hi_iW2 = whiG + (size_t)(l*6+1)*WF_SHORTS;
    const short* hi_sW  = whiG + (size_t)(l*6+2)*WF_SHORTS;
    const short* hi_rW  = whiG + (size_t)(l*6+3)*WF_SHORTS;
    const short* hi_nW1 = whiG + (size_t)(l*6+4)*WF_SHORTS;
    const short* hi_nW2 = whiG + (size_t)(l*6+5)*WF_SHORTS;
    const short* lo_iW1 = wloG + (size_t)(l*6+0)*WF_SHORTS;
    const short* lo_iW2 = wloG + (size_t)(l*6+1)*WF_SHORTS;
    const short* lo_sW  = wloG + (size_t)(l*6+2)*WF_SHORTS;
    const short* lo_rW  = wloG + (size_t)(l*6+3)*WF_SHORTS;
    const short* lo_nW1 = wloG + (size_t)(l*6+4)*WF_SHORTS;
    const short* lo_nW2 = wloG + (size_t)(l*6+5)*WF_SHORTS;

    // intra GINE stage1 (CSR gather)
    k_gine_gather2<<<G_FH4, 256, 0, stream>>>(hmid, h, ea_flat, icnt, irow, ies, FF, CAP_I);
    // MLP via split-bf16 MFMA; W2 pass fuses BN-stats partial accumulation
    k_mm_mfma<<<G_MM_F, 256, 0, stream>>>(hmid, tbuf, FF, hi_iW1, lo_iW1,
                                          intra_b1 + (size_t)l*H, 1, nullptr);
    k_mm_mfma_stats<<<G_MM_F, 256, 0, stream>>>(tbuf, hmid, FF, hi_iW2, lo_iW2,
                                                intra_b2 + (size_t)l*H, statsA);
    k_bnfin_par<<<H, 256, 0, stream>>>(statsA, G_MM_F, FF, muinvA);

    // HT root gather to canonical nodes
    k_canon<<<G_NH4, 256, 0, stream>>>(canon, h, htw, rfi);
    // r2[s] = h[rfi[s]] @ root_W + root_b
    k_mm_mfma<<<G_MM_S, 256, 0, stream>>>(h, r2, SS, hi_rW, lo_rW,
                                          root_b + (size_t)l*H, 0, rfi);

    // inter GINE (CSR gather)
    k_gine_gather2<<<G_NH4, 256, 0, stream>>>(agg2, canon, edge_attr, ecnt, erow, ees, NN, CAP_E);
    k_mm_mfma<<<G_MM_N, 256, 0, stream>>>(agg2, tbuf, NN, hi_nW1, lo_nW1,
                                          inter_b1 + (size_t)l*H, 1, nullptr);
    k_mm_mfma<<<G_MM_N, 256, 0, stream>>>(tbuf, agg2, NN, hi_nW2, lo_nW2,
                                          inter_b2 + (size_t)l*H, 0, nullptr);
    k_bnstats_p<<<G_BN_S, 256, 0, stream>>>(agg2, NN, statsB);
    k_bnfin_par<<<H, 256, 0, stream>>>(statsB, G_BN_S*2, NN, muinvB);
    k_bnapply<<<G_NH4, 256, 0, stream>>>(agg2, muinvB, inter_bn_g + (size_t)l*H,
                                         inter_bn_b + (size_t)l*H, NN);

    // r1 = h @ self_W + self_b
    k_mm_mfma<<<G_MM_F, 256, 0, stream>>>(h, tbuf, FF, hi_sW, lo_sW,
                                          self_b + (size_t)l*H, 0, nullptr);
    // combine -> new h (coalesced float4 streaming)
    k_combine<<<G_FH4, 256, 0, stream>>>(h, hmid, tbuf, r2, agg2, muinvA,
                                         intra_bn_g + (size_t)l*H,
                                         intra_bn_b + (size_t)l*H, node_ids);
  }

  // readout
  k_hsub<<<G_SH4, 256, 0, stream>>>(hsub, h);
  k_poolw<<<G_N, 256, 0, stream>>>(poolw, lp, alpha_pool);
  k_nodeemb<<<G_NH4, 256, 0, stream>>>(nemb, hsub, poolw);
  k_bnstats_p<<<G_BN_S, 256, 0, stream>>>(nemb, NN, statsB);
  k_bnfin_par<<<H, 256, 0, stream>>>(statsB, G_BN_S*2, NN, muinvB);
  k_out<<<(NBATCH*H+255)/256, 256, 0, stream>>>(out, nemb, muinvB, ro_bn_g, ro_bn_b);
}